// Round 1
// baseline (946.420 us; speedup 1.0000x reference)
//
#include <hip/hip_runtime.h>
#include <math.h>

// ---------------------------------------------------------------------------
// BNAF flow (DIM=64, HID=32, B=1024), fp32 baseline.
// Layers per flow: (2048,64) -> (2048,2048) -> (64,2048), masked weight-norm,
// tanh between, log-space Jacobian via 32-term logsumexp, gate+reversal.
// ---------------------------------------------------------------------------

#define DIMN 64
#define BATCH 1024
#define HIDF 2048   // DIM*HID

__device__ __forceinline__ float softplusf_(float t) {
    return fmaxf(t, 0.f) + log1pf(__expf(-fabsf(t)));
}
// log(1 - tanh(x)^2) = -2*(x - log2 + softplus(-2x))
__device__ __forceinline__ float logsech2f_(float x) {
    return -2.f * (x - 0.6931471805599453f + softplusf_(-2.f * x));
}

// ---------------------------------------------------------------------------
// prep: one wave (64 threads) per output row r of W (out_f x in_f).
//  w = exp(W) on diag block, W strictly below (block-wise), 0 above.
//  wsn = sum(w^2); wn = exp(dw)*w/sqrt(wsn)  (optionally transposed store)
//  g[r*ib + (c-c0)] = dw + W - 0.5*log(wsn)  for diag-block cols.
// ---------------------------------------------------------------------------
__global__ __launch_bounds__(64) void prep_kernel(
    const float* __restrict__ W, const float* __restrict__ dw,
    float* __restrict__ wn, float* __restrict__ g,
    int out_f, int in_f, int ob, int ib, int transpose)
{
    int r = blockIdx.x;
    int lane = threadIdx.x;
    int d = r / ob;
    int c0 = d * ib;
    int c1 = c0 + ib;
    const float* Wr = W + (size_t)r * in_f;

    float ss = 0.f;
    for (int c = lane; c < in_f; c += 64) {
        float wraw = Wr[c];
        float wv = (c < c0) ? wraw : ((c < c1) ? __expf(wraw) : 0.f);
        ss += wv * wv;
    }
    for (int off = 32; off > 0; off >>= 1) ss += __shfl_xor(ss, off, 64);

    float dwr = dw[r];
    float scale = __expf(dwr) / sqrtf(ss);
    float logt = dwr - 0.5f * __logf(ss);

    for (int c = lane; c < in_f; c += 64) {
        float wraw = Wr[c];
        float wv = (c < c0) ? wraw : ((c < c1) ? __expf(wraw) : 0.f);
        float val = scale * wv;
        if (transpose) wn[(size_t)c * out_f + r] = val;
        else           wn[(size_t)r * in_f + c] = val;
        if (c >= c0 && c < c1) g[(size_t)r * ib + (c - c0)] = logt + wraw;
    }
}

// ---------------------------------------------------------------------------
// gemm0 + act: pre0 = x @ wn0^T + b0 ; h0 = tanh(pre0);
// grad0[b,r] = g0[r] + log(sech^2(pre0)).   wn0T is (64 x 2048) = [c][n].
// grid (8, 256): block covers 256 n x 4 b.
// ---------------------------------------------------------------------------
__global__ __launch_bounds__(256) void gemm0_act(
    const float* __restrict__ xin, const float* __restrict__ wn0T,
    const float* __restrict__ bias, const float* __restrict__ g0,
    float* __restrict__ h0, float* __restrict__ grad0)
{
    __shared__ float xs[4][DIMN];
    int b0 = blockIdx.y * 4;
    int n = blockIdx.x * 256 + threadIdx.x;
    {
        int j = threadIdx.x >> 6, c = threadIdx.x & 63;
        xs[j][c] = xin[(size_t)(b0 + j) * DIMN + c];
    }
    __syncthreads();

    float a0 = 0.f, a1 = 0.f, a2 = 0.f, a3 = 0.f;
#pragma unroll 8
    for (int c = 0; c < DIMN; ++c) {
        float w = wn0T[(size_t)c * HIDF + n];
        a0 += xs[0][c] * w;
        a1 += xs[1][c] * w;
        a2 += xs[2][c] * w;
        a3 += xs[3][c] * w;
    }
    float bv = bias[n], gv = g0[n];
    float p;
    p = a0 + bv; h0[(size_t)(b0+0)*HIDF+n] = tanhf(p); grad0[(size_t)(b0+0)*HIDF+n] = gv + logsech2f_(p);
    p = a1 + bv; h0[(size_t)(b0+1)*HIDF+n] = tanhf(p); grad0[(size_t)(b0+1)*HIDF+n] = gv + logsech2f_(p);
    p = a2 + bv; h0[(size_t)(b0+2)*HIDF+n] = tanhf(p); grad0[(size_t)(b0+2)*HIDF+n] = gv + logsech2f_(p);
    p = a3 + bv; h0[(size_t)(b0+3)*HIDF+n] = tanhf(p); grad0[(size_t)(b0+3)*HIDF+n] = gv + logsech2f_(p);
}

// ---------------------------------------------------------------------------
// Tiled fp32 GEMM (NT): C[m,n] = sum_k A[m,k]*B[n,k] + bias[n]
// BM=BN=64, BK=16, 256 threads, 4x4 acc per thread.
// ---------------------------------------------------------------------------
#define BM 64
#define BN 64
#define BK 16
__global__ __launch_bounds__(256) void gemm_nt(
    const float* __restrict__ A, const float* __restrict__ B,
    const float* __restrict__ bias, float* __restrict__ C,
    int M, int N, int K)
{
    __shared__ float As[BK][BM + 4];
    __shared__ float Bs[BK][BN + 4];
    int tid = threadIdx.x;
    int m0 = blockIdx.y * BM, n0 = blockIdx.x * BN;
    int lr = tid >> 2;            // 0..63
    int lk = (tid & 3) * 4;       // 0,4,8,12
    const float* Aptr = A + (size_t)(m0 + lr) * K + lk;
    const float* Bptr = B + (size_t)(n0 + lr) * K + lk;
    int tx = tid & 15, ty = tid >> 4;

    float acc[4][4];
#pragma unroll
    for (int i = 0; i < 4; ++i)
#pragma unroll
        for (int j = 0; j < 4; ++j) acc[i][j] = 0.f;

    for (int k0 = 0; k0 < K; k0 += BK) {
        float4 av = *(const float4*)(Aptr + k0);
        float4 bv = *(const float4*)(Bptr + k0);
        __syncthreads();
        As[lk + 0][lr] = av.x; As[lk + 1][lr] = av.y; As[lk + 2][lr] = av.z; As[lk + 3][lr] = av.w;
        Bs[lk + 0][lr] = bv.x; Bs[lk + 1][lr] = bv.y; Bs[lk + 2][lr] = bv.z; Bs[lk + 3][lr] = bv.w;
        __syncthreads();
#pragma unroll
        for (int kk = 0; kk < BK; ++kk) {
            float4 a4 = *(const float4*)&As[kk][ty * 4];
            float4 b4 = *(const float4*)&Bs[kk][tx * 4];
            float ar[4] = {a4.x, a4.y, a4.z, a4.w};
            float br[4] = {b4.x, b4.y, b4.z, b4.w};
#pragma unroll
            for (int i = 0; i < 4; ++i)
#pragma unroll
                for (int j = 0; j < 4; ++j) acc[i][j] = fmaf(ar[i], br[j], acc[i][j]);
        }
    }
#pragma unroll
    for (int i = 0; i < 4; ++i) {
        int m = m0 + ty * 4 + i;
#pragma unroll
        for (int j = 0; j < 4; ++j) {
            int n = n0 + tx * 4 + j;
            C[(size_t)m * N + n] = acc[i][j] + bias[n];
        }
    }
}

// ---------------------------------------------------------------------------
// grad update after layer 1 + tanh (in place on ph = pre1 -> h1):
// new_grad[b,r] = lse_k( g1[r*32+k] + grad0[b, (r&~31)+k] ) + logsech2(pre1)
// grid (8, 1024), 256 threads.
// ---------------------------------------------------------------------------
__global__ __launch_bounds__(256) void gradup1(
    float* ph, const float* __restrict__ grad0,
    const float* __restrict__ g1, float* __restrict__ grad1)
{
    __shared__ float gs[256];
    int b = blockIdx.y;
    int r0 = blockIdx.x * 256;
    int tid = threadIdx.x;
    int r = r0 + tid;
    gs[tid] = grad0[(size_t)b * HIDF + r0 + tid];
    __syncthreads();

    const float* g1r = g1 + (size_t)r * 32;
    int kb = tid & ~31;
    float v[32];
    float m = -3.4e38f;
#pragma unroll
    for (int k = 0; k < 32; ++k) { v[k] = g1r[k] + gs[kb + k]; m = fmaxf(m, v[k]); }
    float s = 0.f;
#pragma unroll
    for (int k = 0; k < 32; ++k) s += __expf(v[k] - m);
    float lse = m + __logf(s);

    size_t idx = (size_t)b * HIDF + r;
    float p = ph[idx];
    ph[idx] = tanhf(p);
    grad1[idx] = lse + logsech2f_(p);
}

// ---------------------------------------------------------------------------
// tail: out2 = h1 @ wn2^T + b2 (wn2T is [c][n], 2048x64), then
// gF[b,d] = lse_k(g2[d*32+k] + grad1[b,d*32+k]);
// mode 0/1: gate-mix, write reversed x_next, ldj write/accum
// mode 2:   out[b] = ldj[b] + sum_d(gF - 0.5*o^2 - 0.5*log(2pi))
// grid 512 blocks (2 b each), 256 threads = 64n x 2b x 2 c-chunks.
// ---------------------------------------------------------------------------
__global__ __launch_bounds__(256) void tail_kernel(
    const float* __restrict__ h1, const float* __restrict__ wn2T,
    const float* __restrict__ b2, const float* __restrict__ g2,
    const float* __restrict__ grad1, const float* __restrict__ x_cur,
    const float* __restrict__ gate, float* __restrict__ x_next,
    float* __restrict__ ldj, float* __restrict__ out, int mode)
{
    __shared__ float hs[2][HIDF];
    __shared__ float o2[2][2][DIMN];
    int b0 = blockIdx.x * 2;
    int tid = threadIdx.x;

    const float4* src = (const float4*)(h1 + (size_t)b0 * HIDF);
    float4* dst = (float4*)&hs[0][0];
#pragma unroll
    for (int i = tid; i < 2 * HIDF / 4; i += 256) dst[i] = src[i];
    __syncthreads();

    {
        int n = tid & 63, jb = (tid >> 6) & 1, jc = tid >> 7;
        const float* hrow = &hs[jb][jc * 1024];
        const float* wp = wn2T + (size_t)jc * 1024 * DIMN + n;
        float acc = 0.f;
#pragma unroll 8
        for (int c = 0; c < 1024; ++c) acc += hrow[c] * wp[(size_t)c * DIMN];
        o2[jb][jc][n] = acc;
    }
    __syncthreads();

    if (tid < 128) {
        int jb = tid >> 6, n = tid & 63;
        int b = b0 + jb;
        float o = o2[jb][0][n] + o2[jb][1][n] + b2[n];

        const float* g2r = g2 + n * 32;
        const float* grow = grad1 + (size_t)b * HIDF + n * 32;
        float v[32];
        float m = -3.4e38f;
#pragma unroll
        for (int k = 0; k < 32; ++k) { v[k] = g2r[k] + grow[k]; m = fmaxf(m, v[k]); }
        float s = 0.f;
#pragma unroll
        for (int k = 0; k < 32; ++k) s += __expf(v[k] - m);
        float gF = m + __logf(s);

        float contrib;
        if (mode < 2) {
            float gt = gate[0];
            float sg = 1.f / (1.f + __expf(-gt));
            float xo = sg * o + (1.f - sg) * x_cur[(size_t)b * DIMN + n];
            x_next[(size_t)b * DIMN + (63 - n)] = xo;
            contrib = softplusf_(gF + gt) - softplusf_(gt);
        } else {
            contrib = gF - 0.5f * o * o - 0.91893853320467274f; // -0.5*log(2pi)
        }
        for (int off = 32; off > 0; off >>= 1) contrib += __shfl_xor(contrib, off, 64);
        if (n == 0) {
            if (mode == 0)      ldj[b] = contrib;
            else if (mode == 1) ldj[b] += contrib;
            else                out[b] = ldj[b] + contrib;
        }
    }
}

// ---------------------------------------------------------------------------
extern "C" void kernel_launch(void* const* d_in, const int* in_sizes, int n_in,
                              void* d_out, int out_size, void* d_ws, size_t ws_size,
                              hipStream_t stream)
{
    (void)in_sizes; (void)n_in; (void)out_size; (void)ws_size;

    const float* x = (const float*)d_in[0];
    const float* gates[2] = { (const float*)d_in[28], (const float*)d_in[29] };

    float* ws = (float*)d_ws;
    size_t ofs = 0;
    auto alloc = [&](size_t n) { float* p = ws + ofs; ofs += (n + 63) & ~(size_t)63; return p; };

    float* wn1   = alloc((size_t)HIDF * HIDF);   // 16 MB
    float* h0    = alloc((size_t)BATCH * HIDF);
    float* ph1   = alloc((size_t)BATCH * HIDF);  // pre1 then h1 (in place)
    float* grad0 = alloc((size_t)BATCH * HIDF);
    float* grad1 = alloc((size_t)BATCH * HIDF);
    float* wn0T  = alloc((size_t)DIMN * HIDF);
    float* wn2T  = alloc((size_t)HIDF * DIMN);
    float* g0    = alloc(HIDF);
    float* g1    = alloc((size_t)HIDF * 32);
    float* g2    = alloc((size_t)DIMN * 32);
    float* x1    = alloc((size_t)BATCH * DIMN);
    float* x2    = alloc((size_t)BATCH * DIMN);
    float* ldj   = alloc(BATCH);
    float* outp  = (float*)d_out;

    const float* xcur = x;
    float* xnexts[3] = { x1, x2, nullptr };

    for (int f = 0; f < 3; ++f) {
        const float* W0  = (const float*)d_in[1 + f * 9 + 0];
        const float* dw0 = (const float*)d_in[1 + f * 9 + 1];
        const float* b0  = (const float*)d_in[1 + f * 9 + 2];
        const float* W1  = (const float*)d_in[1 + f * 9 + 3];
        const float* dw1 = (const float*)d_in[1 + f * 9 + 4];
        const float* b1  = (const float*)d_in[1 + f * 9 + 5];
        const float* W2  = (const float*)d_in[1 + f * 9 + 6];
        const float* dw2 = (const float*)d_in[1 + f * 9 + 7];
        const float* b2  = (const float*)d_in[1 + f * 9 + 8];

        // layer 0: W (2048,64), ob=32, ib=1, store transposed (64x2048)
        prep_kernel<<<dim3(HIDF), dim3(64), 0, stream>>>(W0, dw0, wn0T, g0, HIDF, DIMN, 32, 1, 1);
        gemm0_act<<<dim3(8, BATCH / 4), dim3(256), 0, stream>>>(xcur, wn0T, b0, g0, h0, grad0);

        // layer 1: W (2048,2048), ob=ib=32, natural layout
        prep_kernel<<<dim3(HIDF), dim3(64), 0, stream>>>(W1, dw1, wn1, g1, HIDF, HIDF, 32, 32, 0);
        gemm_nt<<<dim3(HIDF / BN, BATCH / BM), dim3(256), 0, stream>>>(h0, wn1, b1, ph1, BATCH, HIDF, HIDF);
        gradup1<<<dim3(HIDF / 256, BATCH), dim3(256), 0, stream>>>(ph1, grad0, g1, grad1);

        // layer 2: W (64,2048), ob=1, ib=32, store transposed (2048x64)
        prep_kernel<<<dim3(DIMN), dim3(64), 0, stream>>>(W2, dw2, wn2T, g2, DIMN, HIDF, 1, 32, 1);

        tail_kernel<<<dim3(BATCH / 2), dim3(256), 0, stream>>>(
            ph1, wn2T, b2, g2, grad1, xcur,
            (f < 2) ? gates[f] : nullptr, xnexts[f], ldj, outp, f);

        xcur = (f == 0) ? x1 : x2;
    }
}

// Round 3
// 665.568 us; speedup vs baseline: 1.4220x; 1.4220x over previous
//
#include <hip/hip_runtime.h>
#include <hip/hip_bf16.h>
#include <math.h>

// ---------------------------------------------------------------------------
// BNAF flow (DIM=64, HID=32, B=1024).
// Layer-1 GEMM (1024x2048x2048) now bf16 MFMA; rest fp32.
// ---------------------------------------------------------------------------

#define DIMN 64
#define BATCH 1024
#define HIDF 2048   // DIM*HID

typedef __attribute__((ext_vector_type(8))) short short8;
typedef __attribute__((ext_vector_type(4))) float floatx4;

__device__ __forceinline__ float softplusf_(float t) {
    return fmaxf(t, 0.f) + log1pf(__expf(-fabsf(t)));
}
// log(1 - tanh(x)^2) = -2*(x - log2 + softplus(-2x))
__device__ __forceinline__ float logsech2f_(float x) {
    return -2.f * (x - 0.6931471805599453f + softplusf_(-2.f * x));
}

__device__ __forceinline__ void gl_lds16(const void* g, void* l) {
    __builtin_amdgcn_global_load_lds(
        (const __attribute__((address_space(1))) unsigned int*)g,
        (__attribute__((address_space(3))) unsigned int*)l, 16, 0, 0);
}

// ---------------------------------------------------------------------------
// prep: one wave per output row r of W (out_f x in_f).
//  w = exp(W) on diag block, W strictly below (block-wise), 0 above.
//  wsn = sum(w^2); wn = exp(dw)*w/sqrt(wsn)
//  g[r*ib + (c-c0)] = dw + W - 0.5*log(wsn) for diag-block cols.
// bf16out: wn stored as bf16 (natural layout only), else fp32 (opt transpose)
// ---------------------------------------------------------------------------
__global__ __launch_bounds__(64) void prep_kernel(
    const float* __restrict__ W, const float* __restrict__ dw,
    void* __restrict__ wn_out, float* __restrict__ g,
    int out_f, int in_f, int ob, int ib, int transpose, int bf16out)
{
    int r = blockIdx.x;
    int lane = threadIdx.x;
    int d = r / ob;
    int c0 = d * ib;
    int c1 = c0 + ib;
    const float* Wr = W + (size_t)r * in_f;

    float ss = 0.f;
    for (int c = lane; c < in_f; c += 64) {
        float wraw = Wr[c];
        float wv = (c < c0) ? wraw : ((c < c1) ? __expf(wraw) : 0.f);
        ss += wv * wv;
    }
    for (int off = 32; off > 0; off >>= 1) ss += __shfl_xor(ss, off, 64);

    float dwr = dw[r];
    float scale = __expf(dwr) / sqrtf(ss);
    float logt = dwr - 0.5f * __logf(ss);

    for (int c = lane; c < in_f; c += 64) {
        float wraw = Wr[c];
        float wv = (c < c0) ? wraw : ((c < c1) ? __expf(wraw) : 0.f);
        float val = scale * wv;
        if (bf16out) {
            ((__hip_bfloat16*)wn_out)[(size_t)r * in_f + c] = __float2bfloat16(val);
        } else if (transpose) {
            ((float*)wn_out)[(size_t)c * out_f + r] = val;
        } else {
            ((float*)wn_out)[(size_t)r * in_f + c] = val;
        }
        if (c >= c0 && c < c1) g[(size_t)r * ib + (c - c0)] = logt + wraw;
    }
}

// ---------------------------------------------------------------------------
// gemm0 + act: pre0 = x @ wn0^T + b0 ; h0 = tanh(pre0) (bf16);
// grad0[b,r] = g0[r] + log(sech^2(pre0)).  wn0T is (64 x 2048) = [c][n].
// ---------------------------------------------------------------------------
__global__ __launch_bounds__(256) void gemm0_act(
    const float* __restrict__ xin, const float* __restrict__ wn0T,
    const float* __restrict__ bias, const float* __restrict__ g0,
    __hip_bfloat16* __restrict__ h0, float* __restrict__ grad0)
{
    __shared__ float xs[4][DIMN];
    int b0 = blockIdx.y * 4;
    int n = blockIdx.x * 256 + threadIdx.x;
    {
        int j = threadIdx.x >> 6, c = threadIdx.x & 63;
        xs[j][c] = xin[(size_t)(b0 + j) * DIMN + c];
    }
    __syncthreads();

    float a0 = 0.f, a1 = 0.f, a2 = 0.f, a3 = 0.f;
#pragma unroll 8
    for (int c = 0; c < DIMN; ++c) {
        float w = wn0T[(size_t)c * HIDF + n];
        a0 += xs[0][c] * w;
        a1 += xs[1][c] * w;
        a2 += xs[2][c] * w;
        a3 += xs[3][c] * w;
    }
    float bv = bias[n], gv = g0[n];
    float p;
    p = a0 + bv; h0[(size_t)(b0+0)*HIDF+n] = __float2bfloat16(tanhf(p)); grad0[(size_t)(b0+0)*HIDF+n] = gv + logsech2f_(p);
    p = a1 + bv; h0[(size_t)(b0+1)*HIDF+n] = __float2bfloat16(tanhf(p)); grad0[(size_t)(b0+1)*HIDF+n] = gv + logsech2f_(p);
    p = a2 + bv; h0[(size_t)(b0+2)*HIDF+n] = __float2bfloat16(tanhf(p)); grad0[(size_t)(b0+2)*HIDF+n] = gv + logsech2f_(p);
    p = a3 + bv; h0[(size_t)(b0+3)*HIDF+n] = __float2bfloat16(tanhf(p)); grad0[(size_t)(b0+3)*HIDF+n] = gv + logsech2f_(p);
}

// ---------------------------------------------------------------------------
// bf16 MFMA GEMM (NT): C[m,n] = sum_k A[m,k]*B[n,k] + bias[n]
// A: M x K bf16, B: N x K bf16, C: M x N fp32.
// Tile 64x128, BK=32, 256 threads (4 waves, each 32x64 = 2x4 MFMA 16x16x32).
// global_load_lds width-16 staging (m97 pattern).
// ---------------------------------------------------------------------------
#define GBM 64
#define GBN 128
#define GBK 32
__global__ __launch_bounds__(256) void gemm_bf16(
    const __hip_bfloat16* __restrict__ A, const __hip_bfloat16* __restrict__ B,
    const float* __restrict__ bias, float* __restrict__ C,
    int M, int N, int K)
{
    __shared__ short As[GBM * GBK];   // 4 KB, row-major [m][k]
    __shared__ short Bs[GBN * GBK];   // 8 KB, row-major [n][k]
    int tid = threadIdx.x;
    int lane = tid & 63;
    int wave = tid >> 6;
    int m0 = blockIdx.y * GBM;
    int n0 = blockIdx.x * GBN;
    int wr = wave & 1;    // row half: 32 rows
    int wc = wave >> 1;   // col half: 64 cols

    // staging chunk indices (16 B chunks; 4 chunks per 64 B row-slice)
    int ca = wave * 64 + lane;                 // A: 256 chunks
    int cb0 = wave * 128 + lane;               // B: 512 chunks, 2 instrs
    int cb1 = cb0 + 64;
    const char* agp = (const char*)(A + (size_t)(m0 + (ca >> 2)) * K) + (ca & 3) * 16;
    const char* bgp0 = (const char*)(B + (size_t)(n0 + (cb0 >> 2)) * K) + (cb0 & 3) * 16;
    const char* bgp1 = (const char*)(B + (size_t)(n0 + (cb1 >> 2)) * K) + (cb1 & 3) * 16;
    char* alds = (char*)As + wave * 1024;
    char* blds0 = (char*)Bs + wave * 2048;
    char* blds1 = (char*)Bs + wave * 2048 + 1024;

    floatx4 acc[2][4];
#pragma unroll
    for (int i = 0; i < 2; ++i)
#pragma unroll
        for (int j = 0; j < 4; ++j) acc[i][j] = (floatx4){0.f, 0.f, 0.f, 0.f};

    int rf = lane & 15;
    int koff = (lane >> 4) * 8;

    for (int k0 = 0; k0 < K; k0 += GBK) {
        __syncthreads();
        size_t kb = (size_t)k0 * 2;
        gl_lds16(agp + kb, alds);
        gl_lds16(bgp0 + kb, blds0);
        gl_lds16(bgp1 + kb, blds1);
        __syncthreads();

        short8 af[2], bf[4];
#pragma unroll
        for (int i = 0; i < 2; ++i)
            af[i] = *(const short8*)&As[(wr * 32 + i * 16 + rf) * GBK + koff];
#pragma unroll
        for (int j = 0; j < 4; ++j)
            bf[j] = *(const short8*)&Bs[(wc * 64 + j * 16 + rf) * GBK + koff];
#pragma unroll
        for (int i = 0; i < 2; ++i)
#pragma unroll
            for (int j = 0; j < 4; ++j)
                acc[i][j] = __builtin_amdgcn_mfma_f32_16x16x32_bf16(af[i], bf[j], acc[i][j], 0, 0, 0);
    }

    // epilogue: C/D layout col=lane&15, row=(lane>>4)*4+reg
    int col = lane & 15;
    int rq = (lane >> 4) * 4;
#pragma unroll
    for (int i = 0; i < 2; ++i) {
#pragma unroll
        for (int j = 0; j < 4; ++j) {
            int n = n0 + wc * 64 + j * 16 + col;
            float bv = bias[n];
            float* cp = C + (size_t)(m0 + wr * 32 + i * 16 + rq) * N + n;
            cp[0 * N] = acc[i][j][0] + bv;
            cp[1 * N] = acc[i][j][1] + bv;
            cp[2 * N] = acc[i][j][2] + bv;
            cp[3 * N] = acc[i][j][3] + bv;
        }
    }
}

// ---------------------------------------------------------------------------
// grad update after layer 1 + tanh (in place on ph = pre1 -> h1):
// new_grad[b,r] = lse_k( g1[r*32+k] + grad0[b, (r&~31)+k] ) + logsech2(pre1)
// ---------------------------------------------------------------------------
__global__ __launch_bounds__(256) void gradup1(
    float* ph, const float* __restrict__ grad0,
    const float* __restrict__ g1, float* __restrict__ grad1)
{
    __shared__ float gs[256];
    int b = blockIdx.y;
    int r0 = blockIdx.x * 256;
    int tid = threadIdx.x;
    int r = r0 + tid;
    gs[tid] = grad0[(size_t)b * HIDF + r0 + tid];
    __syncthreads();

    const float* g1r = g1 + (size_t)r * 32;
    int kb = tid & ~31;
    float v[32];
    float m = -3.4e38f;
#pragma unroll
    for (int k = 0; k < 32; ++k) { v[k] = g1r[k] + gs[kb + k]; m = fmaxf(m, v[k]); }
    float s = 0.f;
#pragma unroll
    for (int k = 0; k < 32; ++k) s += __expf(v[k] - m);
    float lse = m + __logf(s);

    size_t idx = (size_t)b * HIDF + r;
    float p = ph[idx];
    ph[idx] = tanhf(p);
    grad1[idx] = lse + logsech2f_(p);
}

// ---------------------------------------------------------------------------
// tail: out2 = h1 @ wn2^T + b2 (wn2T is [c][n], 2048x64), then
// gF[b,d] = lse_k(g2[d*32+k] + grad1[b,d*32+k]);
// mode 0/1: gate-mix, write reversed x_next, ldj write/accum
// mode 2:   out[b] = ldj[b] + sum_d(gF - 0.5*o^2 - 0.5*log(2pi))
// ---------------------------------------------------------------------------
__global__ __launch_bounds__(256) void tail_kernel(
    const float* __restrict__ h1, const float* __restrict__ wn2T,
    const float* __restrict__ b2, const float* __restrict__ g2,
    const float* __restrict__ grad1, const float* __restrict__ x_cur,
    const float* __restrict__ gate, float* __restrict__ x_next,
    float* __restrict__ ldj, float* __restrict__ out, int mode)
{
    __shared__ float hs[2][HIDF];
    __shared__ float o2[2][2][DIMN];
    int b0 = blockIdx.x * 2;
    int tid = threadIdx.x;

    const float4* src = (const float4*)(h1 + (size_t)b0 * HIDF);
    float4* dst = (float4*)&hs[0][0];
#pragma unroll
    for (int i = tid; i < 2 * HIDF / 4; i += 256) dst[i] = src[i];
    __syncthreads();

    {
        int n = tid & 63, jb = (tid >> 6) & 1, jc = tid >> 7;
        const float* hrow = &hs[jb][jc * 1024];
        const float* wp = wn2T + (size_t)jc * 1024 * DIMN + n;
        float acc = 0.f;
#pragma unroll 8
        for (int c = 0; c < 1024; ++c) acc += hrow[c] * wp[(size_t)c * DIMN];
        o2[jb][jc][n] = acc;
    }
    __syncthreads();

    if (tid < 128) {
        int jb = tid >> 6, n = tid & 63;
        int b = b0 + jb;
        float o = o2[jb][0][n] + o2[jb][1][n] + b2[n];

        const float* g2r = g2 + n * 32;
        const float* grow = grad1 + (size_t)b * HIDF + n * 32;
        float v[32];
        float m = -3.4e38f;
#pragma unroll
        for (int k = 0; k < 32; ++k) { v[k] = g2r[k] + grow[k]; m = fmaxf(m, v[k]); }
        float s = 0.f;
#pragma unroll
        for (int k = 0; k < 32; ++k) s += __expf(v[k] - m);
        float gF = m + __logf(s);

        float contrib;
        if (mode < 2) {
            float gt = gate[0];
            float sg = 1.f / (1.f + __expf(-gt));
            float xo = sg * o + (1.f - sg) * x_cur[(size_t)b * DIMN + n];
            x_next[(size_t)b * DIMN + (63 - n)] = xo;
            contrib = softplusf_(gF + gt) - softplusf_(gt);
        } else {
            contrib = gF - 0.5f * o * o - 0.91893853320467274f; // -0.5*log(2pi)
        }
        for (int off = 32; off > 0; off >>= 1) contrib += __shfl_xor(contrib, off, 64);
        if (n == 0) {
            if (mode == 0)      ldj[b] = contrib;
            else if (mode == 1) ldj[b] += contrib;
            else                out[b] = ldj[b] + contrib;
        }
    }
}

// ---------------------------------------------------------------------------
extern "C" void kernel_launch(void* const* d_in, const int* in_sizes, int n_in,
                              void* d_out, int out_size, void* d_ws, size_t ws_size,
                              hipStream_t stream)
{
    (void)in_sizes; (void)n_in; (void)out_size; (void)ws_size;

    const float* x = (const float*)d_in[0];
    const float* gates[2] = { (const float*)d_in[28], (const float*)d_in[29] };

    char* ws = (char*)d_ws;
    size_t ofs = 0;
    auto alloc = [&](size_t bytes) { char* p = ws + ofs; ofs += (bytes + 255) & ~(size_t)255; return p; };

    __hip_bfloat16* wn1 = (__hip_bfloat16*)alloc((size_t)HIDF * HIDF * 2);  // 8 MB
    __hip_bfloat16* h0  = (__hip_bfloat16*)alloc((size_t)BATCH * HIDF * 2); // 4 MB
    float* ph1   = (float*)alloc((size_t)BATCH * HIDF * 4);  // pre1 then h1 in place
    float* grad0 = (float*)alloc((size_t)BATCH * HIDF * 4);
    float* grad1 = (float*)alloc((size_t)BATCH * HIDF * 4);
    float* wn0T  = (float*)alloc((size_t)DIMN * HIDF * 4);
    float* wn2T  = (float*)alloc((size_t)HIDF * DIMN * 4);
    float* g0    = (float*)alloc(HIDF * 4);
    float* g1    = (float*)alloc((size_t)HIDF * 32 * 4);
    float* g2    = (float*)alloc((size_t)DIMN * 32 * 4);
    float* x1    = (float*)alloc((size_t)BATCH * DIMN * 4);
    float* x2    = (float*)alloc((size_t)BATCH * DIMN * 4);
    float* ldj   = (float*)alloc(BATCH * 4);
    float* outp  = (float*)d_out;

    const float* xcur = x;
    float* xnexts[3] = { x1, x2, nullptr };

    for (int f = 0; f < 3; ++f) {
        const float* W0  = (const float*)d_in[1 + f * 9 + 0];
        const float* dw0 = (const float*)d_in[1 + f * 9 + 1];
        const float* b0  = (const float*)d_in[1 + f * 9 + 2];
        const float* W1  = (const float*)d_in[1 + f * 9 + 3];
        const float* dw1 = (const float*)d_in[1 + f * 9 + 4];
        const float* b1  = (const float*)d_in[1 + f * 9 + 5];
        const float* W2  = (const float*)d_in[1 + f * 9 + 6];
        const float* dw2 = (const float*)d_in[1 + f * 9 + 7];
        const float* b2  = (const float*)d_in[1 + f * 9 + 8];

        // layer 0: W (2048,64), ob=32, ib=1, fp32 transposed (64x2048)
        prep_kernel<<<dim3(HIDF), dim3(64), 0, stream>>>(W0, dw0, wn0T, g0, HIDF, DIMN, 32, 1, 1, 0);
        gemm0_act<<<dim3(8, BATCH / 4), dim3(256), 0, stream>>>(xcur, wn0T, b0, g0, h0, grad0);

        // layer 1: W (2048,2048), ob=ib=32, bf16 natural layout
        prep_kernel<<<dim3(HIDF), dim3(64), 0, stream>>>(W1, dw1, wn1, g1, HIDF, HIDF, 32, 32, 0, 1);
        gemm_bf16<<<dim3(HIDF / GBN, BATCH / GBM), dim3(256), 0, stream>>>(h0, wn1, b1, ph1, BATCH, HIDF, HIDF);
        gradup1<<<dim3(HIDF / 256, BATCH), dim3(256), 0, stream>>>(ph1, grad0, g1, grad1);

        // layer 2: W (64,2048), ob=1, ib=32, fp32 transposed (2048x64)
        prep_kernel<<<dim3(DIMN), dim3(64), 0, stream>>>(W2, dw2, wn2T, g2, DIMN, HIDF, 1, 32, 1, 0);

        tail_kernel<<<dim3(BATCH / 2), dim3(256), 0, stream>>>(
            ph1, wn2T, b2, g2, grad1, xcur,
            (f < 2) ? gates[f] : nullptr, xnexts[f], ldj, outp, f);

        xcur = (f == 0) ? x1 : x2;
    }
}

// Round 4
// 497.542 us; speedup vs baseline: 1.9022x; 1.3377x over previous
//
#include <hip/hip_runtime.h>
#include <hip/hip_bf16.h>
#include <math.h>

// ---------------------------------------------------------------------------
// BNAF flow (DIM=64, HID=32, B=1024).
// Layer-1 GEMM and layer-2 GEMM bf16 MFMA; layer-0 fused fp32; log-Jacobian
// propagation in fp32.
// ---------------------------------------------------------------------------

#define DIMN 64
#define BATCH 1024
#define HIDF 2048   // DIM*HID

typedef __attribute__((ext_vector_type(8))) short short8;
typedef __attribute__((ext_vector_type(4))) float floatx4;

__device__ __forceinline__ float softplusf_(float t) {
    return fmaxf(t, 0.f) + log1pf(__expf(-fabsf(t)));
}
// log(1 - tanh(x)^2) = -2*(x - log2 + softplus(-2x))
__device__ __forceinline__ float logsech2f_(float x) {
    return -2.f * (x - 0.6931471805599453f + softplusf_(-2.f * x));
}

__device__ __forceinline__ void gl_lds16(const void* g, void* l) {
    __builtin_amdgcn_global_load_lds(
        (const __attribute__((address_space(1))) unsigned int*)g,
        (__attribute__((address_space(3))) unsigned int*)l, 16, 0, 0);
}

// ---------------------------------------------------------------------------
// prep: one wave per output row r of W (out_f x INF). Single pass over W
// (weights cached in registers).
//  w = exp(W) on diag block, W strictly below (block-wise), 0 above.
//  wsn = sum(w^2); wn = exp(dw)*w/sqrt(wsn)
//  g[r*ib + k] = dw + W[r][c0+k] - 0.5*log(wsn) for diag-block cols.
// ---------------------------------------------------------------------------
template<int INF>
__global__ __launch_bounds__(64) void prep_kernel_t(
    const float* __restrict__ W, const float* __restrict__ dw,
    void* __restrict__ wn_out, float* __restrict__ g,
    int out_f, int ob, int ib, int transpose, int bf16out)
{
    constexpr int NI = INF / 64;
    int r = blockIdx.x;
    int lane = threadIdx.x;
    int d = r / ob;
    int c0 = d * ib;
    int c1 = c0 + ib;
    const float* Wr = W + (size_t)r * INF;

    float vv[NI];
    float ss = 0.f;
#pragma unroll
    for (int i = 0; i < NI; ++i) {
        int c = lane + i * 64;
        float wraw = Wr[c];
        float wv = (c < c0) ? wraw : ((c < c1) ? __expf(wraw) : 0.f);
        vv[i] = wv;
        ss += wv * wv;
    }
    for (int off = 32; off > 0; off >>= 1) ss += __shfl_xor(ss, off, 64);

    float dwr = dw[r];
    float scale = __expf(dwr) / sqrtf(ss);
    float logt = dwr - 0.5f * __logf(ss);

#pragma unroll
    for (int i = 0; i < NI; ++i) {
        int c = lane + i * 64;
        float val = scale * vv[i];
        if (bf16out) {
            ((__hip_bfloat16*)wn_out)[(size_t)r * INF + c] = __float2bfloat16(val);
        } else if (transpose) {
            ((float*)wn_out)[(size_t)c * out_f + r] = val;
        } else {
            ((float*)wn_out)[(size_t)r * INF + c] = val;
        }
    }
    if (lane < ib) g[(size_t)r * ib + lane] = logt + Wr[c0 + lane];
}

// ---------------------------------------------------------------------------
// gemm0 + act: pre0 = x @ wn0^T + b0 ; h0 = tanh(pre0) (bf16);
// grad0[b,r] = g0[r] + log(sech^2(pre0)).  wn0T is (64 x 2048) = [c][n].
// grid (8, 64): block = 256 n x 16 b.
// ---------------------------------------------------------------------------
__global__ __launch_bounds__(256) void gemm0_act(
    const float* __restrict__ xin, const float* __restrict__ wn0T,
    const float* __restrict__ bias, const float* __restrict__ g0,
    __hip_bfloat16* __restrict__ h0, float* __restrict__ grad0)
{
    __shared__ float xs[16][DIMN];
    int b0 = blockIdx.y * 16;
    int n = blockIdx.x * 256 + threadIdx.x;
    {
        const float4* src = (const float4*)(xin + (size_t)b0 * DIMN);
        ((float4*)xs)[threadIdx.x] = src[threadIdx.x];  // 256 * 16B = 4 KB
    }
    __syncthreads();

    float acc[16];
#pragma unroll
    for (int j = 0; j < 16; ++j) acc[j] = 0.f;

#pragma unroll 4
    for (int c4 = 0; c4 < 16; ++c4) {
        int c = c4 * 4;
        float w0 = wn0T[(size_t)(c + 0) * HIDF + n];
        float w1 = wn0T[(size_t)(c + 1) * HIDF + n];
        float w2 = wn0T[(size_t)(c + 2) * HIDF + n];
        float w3 = wn0T[(size_t)(c + 3) * HIDF + n];
#pragma unroll
        for (int j = 0; j < 16; ++j) {
            float4 x4 = *(const float4*)&xs[j][c];
            acc[j] = fmaf(x4.x, w0, acc[j]);
            acc[j] = fmaf(x4.y, w1, acc[j]);
            acc[j] = fmaf(x4.z, w2, acc[j]);
            acc[j] = fmaf(x4.w, w3, acc[j]);
        }
    }
    float bv = bias[n], gv = g0[n];
#pragma unroll
    for (int j = 0; j < 16; ++j) {
        float p = acc[j] + bv;
        size_t idx = (size_t)(b0 + j) * HIDF + n;
        h0[idx] = __float2bfloat16(tanhf(p));
        grad0[idx] = gv + logsech2f_(p);
    }
}

// ---------------------------------------------------------------------------
// bf16 MFMA GEMM (NT): C[m,n] = sum_k A[m,k]*B[n,k] + bias[n]
// Tile 64x128, BK=32, 256 threads (4 waves, each 32x64 = 2x4 MFMA 16x16x32).
// ---------------------------------------------------------------------------
#define GBM 64
#define GBN 128
#define GBK 32
__global__ __launch_bounds__(256) void gemm_bf16(
    const __hip_bfloat16* __restrict__ A, const __hip_bfloat16* __restrict__ B,
    const float* __restrict__ bias, float* __restrict__ C,
    int M, int N, int K)
{
    __shared__ short As[GBM * GBK];   // 4 KB, row-major [m][k]
    __shared__ short Bs[GBN * GBK];   // 8 KB, row-major [n][k]
    int tid = threadIdx.x;
    int lane = tid & 63;
    int wave = tid >> 6;
    int m0 = blockIdx.y * GBM;
    int n0 = blockIdx.x * GBN;
    int wr = wave & 1;    // row half: 32 rows
    int wc = wave >> 1;   // col half: 64 cols

    int ca = wave * 64 + lane;                 // A: 256 chunks of 16B
    int cb0 = wave * 128 + lane;               // B: 512 chunks, 2 instrs
    int cb1 = cb0 + 64;
    const char* agp = (const char*)(A + (size_t)(m0 + (ca >> 2)) * K) + (ca & 3) * 16;
    const char* bgp0 = (const char*)(B + (size_t)(n0 + (cb0 >> 2)) * K) + (cb0 & 3) * 16;
    const char* bgp1 = (const char*)(B + (size_t)(n0 + (cb1 >> 2)) * K) + (cb1 & 3) * 16;
    char* alds = (char*)As + wave * 1024;
    char* blds0 = (char*)Bs + wave * 2048;
    char* blds1 = (char*)Bs + wave * 2048 + 1024;

    floatx4 acc[2][4];
#pragma unroll
    for (int i = 0; i < 2; ++i)
#pragma unroll
        for (int j = 0; j < 4; ++j) acc[i][j] = (floatx4){0.f, 0.f, 0.f, 0.f};

    int rf = lane & 15;
    int koff = (lane >> 4) * 8;

    for (int k0 = 0; k0 < K; k0 += GBK) {
        __syncthreads();
        size_t kb = (size_t)k0 * 2;
        gl_lds16(agp + kb, alds);
        gl_lds16(bgp0 + kb, blds0);
        gl_lds16(bgp1 + kb, blds1);
        __syncthreads();

        short8 af[2], bf[4];
#pragma unroll
        for (int i = 0; i < 2; ++i)
            af[i] = *(const short8*)&As[(wr * 32 + i * 16 + rf) * GBK + koff];
#pragma unroll
        for (int j = 0; j < 4; ++j)
            bf[j] = *(const short8*)&Bs[(wc * 64 + j * 16 + rf) * GBK + koff];
#pragma unroll
        for (int i = 0; i < 2; ++i)
#pragma unroll
            for (int j = 0; j < 4; ++j)
                acc[i][j] = __builtin_amdgcn_mfma_f32_16x16x32_bf16(af[i], bf[j], acc[i][j], 0, 0, 0);
    }

    int col = lane & 15;
    int rq = (lane >> 4) * 4;
#pragma unroll
    for (int i = 0; i < 2; ++i) {
#pragma unroll
        for (int j = 0; j < 4; ++j) {
            int n = n0 + wc * 64 + j * 16 + col;
            float bv = bias[n];
            float* cp = C + (size_t)(m0 + wr * 32 + i * 16 + rq) * N + n;
            cp[0 * N] = acc[i][j][0] + bv;
            cp[1 * N] = acc[i][j][1] + bv;
            cp[2 * N] = acc[i][j][2] + bv;
            cp[3 * N] = acc[i][j][3] + bv;
        }
    }
}

// ---------------------------------------------------------------------------
// grad update after layer 1 + tanh:
// h1b[b,r] = bf16(tanh(pre1));
// grad1[b,r] = lse_k( g1[r*32+k] + grad0[b,(r&~31)+k] ) + logsech2(pre1)
// ---------------------------------------------------------------------------
__global__ __launch_bounds__(256) void gradup1(
    const float* __restrict__ ph, const float* __restrict__ grad0,
    const float* __restrict__ g1, float* __restrict__ grad1,
    __hip_bfloat16* __restrict__ h1b)
{
    __shared__ float gs[256];
    int b = blockIdx.y;
    int r0 = blockIdx.x * 256;
    int tid = threadIdx.x;
    int r = r0 + tid;
    gs[tid] = grad0[(size_t)b * HIDF + r0 + tid];
    __syncthreads();

    const float* g1r = g1 + (size_t)r * 32;
    int kb = tid & ~31;
    float v[32];
    float m = -3.4e38f;
#pragma unroll
    for (int k = 0; k < 32; ++k) { v[k] = g1r[k] + gs[kb + k]; m = fmaxf(m, v[k]); }
    float s = 0.f;
#pragma unroll
    for (int k = 0; k < 32; ++k) s += __expf(v[k] - m);
    float lse = m + __logf(s);

    size_t idx = (size_t)b * HIDF + r;
    float p = ph[idx];
    h1b[idx] = __float2bfloat16(tanhf(p));
    grad1[idx] = lse + logsech2f_(p);
}

// ---------------------------------------------------------------------------
// init_out2: out2[b][n] = bias2[n]   (1024*64 elements)
// ---------------------------------------------------------------------------
__global__ __launch_bounds__(256) void init_out2(
    float* __restrict__ out2, const float* __restrict__ b2)
{
    int i = blockIdx.x * 256 + threadIdx.x;
    out2[i] = b2[i & 63];
}

// ---------------------------------------------------------------------------
// gemm2_splitk: out2[m,n] += sum_{k in chunk} h1b[m,k]*wn2b[n,k]
// A: 1024x2048 bf16, B: 64x2048 bf16. Block = 64(M) x 64(N) x 128(K-chunk).
// grid (16 kchunks, 16 mtiles), 256 threads (4 waves, each 16 rows x 64 n).
// fp32 atomic accumulation into pre-initialized out2.
// ---------------------------------------------------------------------------
__global__ __launch_bounds__(256) void gemm2_splitk(
    const __hip_bfloat16* __restrict__ A, const __hip_bfloat16* __restrict__ B,
    float* __restrict__ out2)
{
    __shared__ short As2[64 * 128];   // 16 KB [m][k]
    __shared__ short Bs2[64 * 128];   // 16 KB [n][k]
    int tid = threadIdx.x;
    int lane = tid & 63;
    int wave = tid >> 6;
    int k0 = blockIdx.x * 128;
    int m0 = blockIdx.y * 64;

    const char* Ab = (const char*)A;
    const char* Bb = (const char*)B;
#pragma unroll
    for (int is = 0; is < 4; ++is) {
        int ci = is * 256 + tid;          // 0..1023; row = ci>>4, kc = ci&15
        int row = ci >> 4, kc = ci & 15;
        char* ldsbase_a = (char*)As2 + (is * 256 + wave * 64) * 16;
        char* ldsbase_b = (char*)Bs2 + (is * 256 + wave * 64) * 16;
        gl_lds16(Ab + ((size_t)(m0 + row) * HIDF + k0) * 2 + kc * 16, ldsbase_a);
        gl_lds16(Bb + ((size_t)row * HIDF + k0) * 2 + kc * 16, ldsbase_b);
    }
    __syncthreads();

    int rf = lane & 15;
    int koff = (lane >> 4) * 8;

    floatx4 acc[4];
#pragma unroll
    for (int j = 0; j < 4; ++j) acc[j] = (floatx4){0.f, 0.f, 0.f, 0.f};

#pragma unroll
    for (int s = 0; s < 4; ++s) {
        short8 af = *(const short8*)&As2[(wave * 16 + rf) * 128 + s * 32 + koff];
#pragma unroll
        for (int j = 0; j < 4; ++j) {
            short8 bfv = *(const short8*)&Bs2[(j * 16 + rf) * 128 + s * 32 + koff];
            acc[j] = __builtin_amdgcn_mfma_f32_16x16x32_bf16(af, bfv, acc[j], 0, 0, 0);
        }
    }

    int col = lane & 15;
    int rq = (lane >> 4) * 4;
#pragma unroll
    for (int j = 0; j < 4; ++j) {
#pragma unroll
        for (int r = 0; r < 4; ++r) {
            int m = m0 + wave * 16 + rq + r;
            unsafeAtomicAdd(&out2[(size_t)m * DIMN + j * 16 + col], acc[j][r]);
        }
    }
}

// ---------------------------------------------------------------------------
// tail_lite: per (b,n): o = out2[b][n];
// gF = lse_k(g2[n*32+k] + grad1[b,n*32+k]);
// mode 0/1: gate-mix + reversed x_next + ldj write/accum
// mode 2:   out[b] = ldj[b] + sum_n(gF - 0.5*o^2 - 0.5*log(2pi))
// grid 256 blocks x 256 threads; wave = one batch row.
// ---------------------------------------------------------------------------
__global__ __launch_bounds__(256) void tail_lite(
    const float* __restrict__ out2, const float* __restrict__ g2,
    const float* __restrict__ grad1, const float* __restrict__ x_cur,
    const float* __restrict__ gate, float* __restrict__ x_next,
    float* __restrict__ ldj, float* __restrict__ out, int mode)
{
    int tid = threadIdx.x;
    int b = blockIdx.x * 4 + (tid >> 6);
    int n = tid & 63;

    float o = out2[(size_t)b * DIMN + n];

    const float4* grow = (const float4*)(grad1 + (size_t)b * HIDF + n * 32);
    const float4* g2r = (const float4*)(g2 + n * 32);
    float v[32];
    float m = -3.4e38f;
#pragma unroll
    for (int q = 0; q < 8; ++q) {
        float4 gv = grow[q];
        float4 cv = g2r[q];
        v[q*4+0] = gv.x + cv.x; v[q*4+1] = gv.y + cv.y;
        v[q*4+2] = gv.z + cv.z; v[q*4+3] = gv.w + cv.w;
    }
#pragma unroll
    for (int k = 0; k < 32; ++k) m = fmaxf(m, v[k]);
    float s = 0.f;
#pragma unroll
    for (int k = 0; k < 32; ++k) s += __expf(v[k] - m);
    float gF = m + __logf(s);

    float contrib;
    if (mode < 2) {
        float gt = gate[0];
        float sg = 1.f / (1.f + __expf(-gt));
        float xo = sg * o + (1.f - sg) * x_cur[(size_t)b * DIMN + n];
        x_next[(size_t)b * DIMN + (63 - n)] = xo;
        contrib = softplusf_(gF + gt) - softplusf_(gt);
    } else {
        contrib = gF - 0.5f * o * o - 0.91893853320467274f; // -0.5*log(2pi)
    }
    for (int off = 32; off > 0; off >>= 1) contrib += __shfl_xor(contrib, off, 64);
    if (n == 0) {
        if (mode == 0)      ldj[b] = contrib;
        else if (mode == 1) ldj[b] += contrib;
        else                out[b] = ldj[b] + contrib;
    }
}

// ---------------------------------------------------------------------------
extern "C" void kernel_launch(void* const* d_in, const int* in_sizes, int n_in,
                              void* d_out, int out_size, void* d_ws, size_t ws_size,
                              hipStream_t stream)
{
    (void)in_sizes; (void)n_in; (void)out_size; (void)ws_size;

    const float* x = (const float*)d_in[0];
    const float* gates[2] = { (const float*)d_in[28], (const float*)d_in[29] };

    char* ws = (char*)d_ws;
    size_t ofs = 0;
    auto alloc = [&](size_t bytes) { char* p = ws + ofs; ofs += (bytes + 255) & ~(size_t)255; return p; };

    __hip_bfloat16* wn1  = (__hip_bfloat16*)alloc((size_t)HIDF * HIDF * 2);  // 8 MB
    __hip_bfloat16* h0   = (__hip_bfloat16*)alloc((size_t)BATCH * HIDF * 2); // 4 MB
    __hip_bfloat16* h1b  = (__hip_bfloat16*)alloc((size_t)BATCH * HIDF * 2); // 4 MB
    __hip_bfloat16* wn2b = (__hip_bfloat16*)alloc((size_t)DIMN * HIDF * 2);  // 256 KB
    float* ph1   = (float*)alloc((size_t)BATCH * HIDF * 4);
    float* grad0 = (float*)alloc((size_t)BATCH * HIDF * 4);
    float* grad1 = (float*)alloc((size_t)BATCH * HIDF * 4);
    float* wn0T  = (float*)alloc((size_t)DIMN * HIDF * 4);
    float* g0    = (float*)alloc(HIDF * 4);
    float* g1    = (float*)alloc((size_t)HIDF * 32 * 4);
    float* g2    = (float*)alloc((size_t)DIMN * 32 * 4);
    float* out2  = (float*)alloc((size_t)BATCH * DIMN * 4);
    float* x1    = (float*)alloc((size_t)BATCH * DIMN * 4);
    float* x2    = (float*)alloc((size_t)BATCH * DIMN * 4);
    float* ldj   = (float*)alloc(BATCH * 4);
    float* outp  = (float*)d_out;

    const float* xcur = x;
    float* xnexts[3] = { x1, x2, nullptr };

    for (int f = 0; f < 3; ++f) {
        const float* W0  = (const float*)d_in[1 + f * 9 + 0];
        const float* dw0 = (const float*)d_in[1 + f * 9 + 1];
        const float* b0  = (const float*)d_in[1 + f * 9 + 2];
        const float* W1  = (const float*)d_in[1 + f * 9 + 3];
        const float* dw1 = (const float*)d_in[1 + f * 9 + 4];
        const float* b1  = (const float*)d_in[1 + f * 9 + 5];
        const float* W2  = (const float*)d_in[1 + f * 9 + 6];
        const float* dw2 = (const float*)d_in[1 + f * 9 + 7];
        const float* b2  = (const float*)d_in[1 + f * 9 + 8];

        // layer 0: W (2048,64), ob=32, ib=1, fp32 transposed (64x2048)
        prep_kernel_t<DIMN><<<dim3(HIDF), dim3(64), 0, stream>>>(W0, dw0, wn0T, g0, HIDF, 32, 1, 1, 0);
        gemm0_act<<<dim3(8, BATCH / 16), dim3(256), 0, stream>>>(xcur, wn0T, b0, g0, h0, grad0);

        // layer 1: W (2048,2048), ob=ib=32, bf16 natural layout
        prep_kernel_t<HIDF><<<dim3(HIDF), dim3(64), 0, stream>>>(W1, dw1, wn1, g1, HIDF, 32, 32, 0, 1);
        gemm_bf16<<<dim3(HIDF / GBN, BATCH / GBM), dim3(256), 0, stream>>>(h0, wn1, b1, ph1, BATCH, HIDF, HIDF);
        gradup1<<<dim3(HIDF / 256, BATCH), dim3(256), 0, stream>>>(ph1, grad0, g1, grad1, h1b);

        // layer 2: W (64,2048), ob=1, ib=32, bf16 natural (64x2048)
        prep_kernel_t<HIDF><<<dim3(DIMN), dim3(64), 0, stream>>>(W2, dw2, wn2b, g2, DIMN, 1, 32, 0, 1);
        init_out2<<<dim3(BATCH * DIMN / 256), dim3(256), 0, stream>>>(out2, b2);
        gemm2_splitk<<<dim3(HIDF / 128, BATCH / 64), dim3(256), 0, stream>>>(h1b, wn2b, out2);

        tail_lite<<<dim3(BATCH / 4), dim3(256), 0, stream>>>(
            out2, g2, grad1, xcur,
            (f < 2) ? gates[f] : nullptr, xnexts[f], ldj, outp, f);

        xcur = (f == 0) ? x1 : x2;
    }
}

// Round 5
// 453.156 us; speedup vs baseline: 2.0885x; 1.0979x over previous
//
#include <hip/hip_runtime.h>
#include <hip/hip_bf16.h>
#include <math.h>

// ---------------------------------------------------------------------------
// BNAF flow (DIM=64, HID=32, B=1024).
// R5: fused gemm1+act epilogue, 64x64 gemm tile (2 blocks/CU), split-K gemm2
// with partial buffer (no atomics/init), merged prep launch. 18 dispatches.
// ---------------------------------------------------------------------------

#define DIMN 64
#define BATCH 1024
#define HIDF 2048   // DIM*HID

typedef __attribute__((ext_vector_type(8))) short short8;
typedef __attribute__((ext_vector_type(4))) float floatx4;

__device__ __forceinline__ float softplusf_(float t) {
    return fmaxf(t, 0.f) + log1pf(__expf(-fabsf(t)));
}
// log(1 - tanh(x)^2) = -2*(x - log2 + softplus(-2x))
__device__ __forceinline__ float logsech2f_(float x) {
    return -2.f * (x - 0.6931471805599453f + softplusf_(-2.f * x));
}

__device__ __forceinline__ void gl_lds16(const void* g, void* l) {
    __builtin_amdgcn_global_load_lds(
        (const __attribute__((address_space(1))) unsigned int*)g,
        (__attribute__((address_space(3))) unsigned int*)l, 16, 0, 0);
}

// ---------------------------------------------------------------------------
// prep row worker: one wave per output row r of W (out_f x INF).
//  w = exp(W) on diag block, W strictly below (block-wise), 0 above.
//  wsn = sum(w^2); wn = exp(dw)*w/sqrt(wsn)
//  g[r*ib + k] = dw + W[r][c0+k] - 0.5*log(wsn) for diag-block cols.
// ---------------------------------------------------------------------------
template<int INF>
__device__ __forceinline__ void prep_row(
    const float* __restrict__ W, const float* __restrict__ dw,
    void* __restrict__ wn_out, float* __restrict__ g,
    int r, int lane, int out_f, int ob, int ib, int transpose, int bf16out)
{
    constexpr int NI = INF / 64;
    int d = r / ob;
    int c0 = d * ib;
    int c1 = c0 + ib;
    const float* Wr = W + (size_t)r * INF;

    float vv[NI];
    float ss = 0.f;
#pragma unroll
    for (int i = 0; i < NI; ++i) {
        int c = lane + i * 64;
        float wraw = Wr[c];
        float wv = (c < c0) ? wraw : ((c < c1) ? __expf(wraw) : 0.f);
        vv[i] = wv;
        ss += wv * wv;
    }
    for (int off = 32; off > 0; off >>= 1) ss += __shfl_xor(ss, off, 64);

    float dwr = dw[r];
    float scale = __expf(dwr) / sqrtf(ss);
    float logt = dwr - 0.5f * __logf(ss);

#pragma unroll
    for (int i = 0; i < NI; ++i) {
        int c = lane + i * 64;
        float val = scale * vv[i];
        if (bf16out) {
            ((__hip_bfloat16*)wn_out)[(size_t)r * INF + c] = __float2bfloat16(val);
        } else if (transpose) {
            ((float*)wn_out)[(size_t)c * out_f + r] = val;
        } else {
            ((float*)wn_out)[(size_t)r * INF + c] = val;
        }
    }
    if (lane < ib) g[(size_t)r * ib + lane] = logt + Wr[c0 + lane];
}

// one launch for all three layers' preps: grid 2048 + 2048 + 64 = 4160 waves
__global__ __launch_bounds__(64) void prep_all(
    const float* __restrict__ W0, const float* __restrict__ dw0,
    float* __restrict__ wn0T, float* __restrict__ g0,
    const float* __restrict__ W1, const float* __restrict__ dw1,
    __hip_bfloat16* __restrict__ wn1, float* __restrict__ g1,
    const float* __restrict__ W2, const float* __restrict__ dw2,
    __hip_bfloat16* __restrict__ wn2b, float* __restrict__ g2)
{
    int blk = blockIdx.x;
    int lane = threadIdx.x;
    if (blk < HIDF) {
        // layer 0: W (2048,64), ob=32, ib=1, fp32 transposed (64x2048)
        prep_row<DIMN>(W0, dw0, wn0T, g0, blk, lane, HIDF, 32, 1, 1, 0);
    } else if (blk < 2 * HIDF) {
        // layer 1: W (2048,2048), ob=ib=32, bf16 natural
        prep_row<HIDF>(W1, dw1, wn1, g1, blk - HIDF, lane, HIDF, 32, 32, 0, 1);
    } else {
        // layer 2: W (64,2048), ob=1, ib=32, bf16 natural
        prep_row<HIDF>(W2, dw2, wn2b, g2, blk - 2 * HIDF, lane, DIMN, 1, 32, 0, 1);
    }
}

// ---------------------------------------------------------------------------
// gemm0 + act: pre0 = x @ wn0^T + b0 ; h0 = tanh(pre0) (bf16);
// grad0[b,r] = g0[r] + log(sech^2(pre0)).  wn0T is (64 x 2048) = [c][n].
// grid (8, 64): block = 256 n x 16 b.
// ---------------------------------------------------------------------------
__global__ __launch_bounds__(256) void gemm0_act(
    const float* __restrict__ xin, const float* __restrict__ wn0T,
    const float* __restrict__ bias, const float* __restrict__ g0,
    __hip_bfloat16* __restrict__ h0, float* __restrict__ grad0)
{
    __shared__ float xs[16][DIMN];
    int b0 = blockIdx.y * 16;
    int n = blockIdx.x * 256 + threadIdx.x;
    {
        const float4* src = (const float4*)(xin + (size_t)b0 * DIMN);
        ((float4*)xs)[threadIdx.x] = src[threadIdx.x];  // 256 * 16B = 4 KB
    }
    __syncthreads();

    float acc[16];
#pragma unroll
    for (int j = 0; j < 16; ++j) acc[j] = 0.f;

#pragma unroll 4
    for (int c4 = 0; c4 < 16; ++c4) {
        int c = c4 * 4;
        float w0 = wn0T[(size_t)(c + 0) * HIDF + n];
        float w1 = wn0T[(size_t)(c + 1) * HIDF + n];
        float w2 = wn0T[(size_t)(c + 2) * HIDF + n];
        float w3 = wn0T[(size_t)(c + 3) * HIDF + n];
#pragma unroll
        for (int j = 0; j < 16; ++j) {
            float4 x4 = *(const float4*)&xs[j][c];
            acc[j] = fmaf(x4.x, w0, acc[j]);
            acc[j] = fmaf(x4.y, w1, acc[j]);
            acc[j] = fmaf(x4.z, w2, acc[j]);
            acc[j] = fmaf(x4.w, w3, acc[j]);
        }
    }
    float bv = bias[n], gv = g0[n];
#pragma unroll
    for (int j = 0; j < 16; ++j) {
        float p = acc[j] + bv;
        size_t idx = (size_t)(b0 + j) * HIDF + n;
        h0[idx] = __float2bfloat16(tanhf(p));
        grad0[idx] = gv + logsech2f_(p);
    }
}

// ---------------------------------------------------------------------------
// gemm1 + act: pre1 = h0 @ wn1^T + b1 (bf16 MFMA).
// Epilogue: h1b = bf16(tanh(pre1)); lsech = logsech2(pre1) (fp32).
// Tile 64x64, BK=32, 256 threads (4 waves, each 32x32 = 2x2 MFMA 16x16x32).
// grid (N/64=32, M/64=16) = 512 blocks = 2 blocks/CU.
// ---------------------------------------------------------------------------
#define G1K 32
__global__ __launch_bounds__(256) void gemm1_act(
    const __hip_bfloat16* __restrict__ A, const __hip_bfloat16* __restrict__ B,
    const float* __restrict__ bias,
    __hip_bfloat16* __restrict__ h1b, float* __restrict__ lsech)
{
    __shared__ short As[64 * G1K];   // 4 KB [m][k]
    __shared__ short Bs[64 * G1K];   // 4 KB [n][k]
    const int K = HIDF, N = HIDF;
    int tid = threadIdx.x;
    int lane = tid & 63;
    int wave = tid >> 6;
    int m0 = blockIdx.y * 64;
    int n0 = blockIdx.x * 64;
    int wr = wave & 1;    // m half (32 rows)
    int wc = wave >> 1;   // n half (32 cols)

    // staging: 64x32 bf16 = 4 KB = 256 x 16B chunks each for A and B
    int ca = wave * 64 + lane;       // chunk: row = ca>>2, kc = ca&3
    const char* agp = (const char*)(A + (size_t)(m0 + (ca >> 2)) * K) + (ca & 3) * 16;
    const char* bgp = (const char*)(B + (size_t)(n0 + (ca >> 2)) * K) + (ca & 3) * 16;
    char* alds = (char*)As + wave * 1024;
    char* blds = (char*)Bs + wave * 1024;

    floatx4 acc[2][2];
#pragma unroll
    for (int i = 0; i < 2; ++i)
#pragma unroll
        for (int j = 0; j < 2; ++j) acc[i][j] = (floatx4){0.f, 0.f, 0.f, 0.f};

    int rf = lane & 15;
    int koff = (lane >> 4) * 8;

    for (int k0 = 0; k0 < K; k0 += G1K) {
        __syncthreads();
        size_t kb = (size_t)k0 * 2;
        gl_lds16(agp + kb, alds);
        gl_lds16(bgp + kb, blds);
        __syncthreads();

        short8 af[2], bf[2];
#pragma unroll
        for (int i = 0; i < 2; ++i)
            af[i] = *(const short8*)&As[(wr * 32 + i * 16 + rf) * G1K + koff];
#pragma unroll
        for (int j = 0; j < 2; ++j)
            bf[j] = *(const short8*)&Bs[(wc * 32 + j * 16 + rf) * G1K + koff];
#pragma unroll
        for (int i = 0; i < 2; ++i)
#pragma unroll
            for (int j = 0; j < 2; ++j)
                acc[i][j] = __builtin_amdgcn_mfma_f32_16x16x32_bf16(af[i], bf[j], acc[i][j], 0, 0, 0);
    }

    // C/D layout: col = lane&15, row = (lane>>4)*4 + reg
    int col = lane & 15;
    int rq = (lane >> 4) * 4;
#pragma unroll
    for (int i = 0; i < 2; ++i) {
#pragma unroll
        for (int j = 0; j < 2; ++j) {
            int n = n0 + wc * 32 + j * 16 + col;
            float bv = bias[n];
#pragma unroll
            for (int r = 0; r < 4; ++r) {
                int m = m0 + wr * 32 + i * 16 + rq + r;
                float p = acc[i][j][r] + bv;
                size_t idx = (size_t)m * N + n;
                h1b[idx] = __float2bfloat16(tanhf(p));
                lsech[idx] = logsech2f_(p);
            }
        }
    }
}

// ---------------------------------------------------------------------------
// grad update after layer 1:
// grad1[b,r] = lse_k( g1[r*32+k] + grad0[b,(r&~31)+k] ) + lsech[b,r]
// ---------------------------------------------------------------------------
__global__ __launch_bounds__(256) void gradup1(
    const float* __restrict__ lsech, const float* __restrict__ grad0,
    const float* __restrict__ g1, float* __restrict__ grad1)
{
    __shared__ float gs[256];
    int b = blockIdx.y;
    int r0 = blockIdx.x * 256;
    int tid = threadIdx.x;
    int r = r0 + tid;
    gs[tid] = grad0[(size_t)b * HIDF + r0 + tid];
    __syncthreads();

    const float* g1r = g1 + (size_t)r * 32;
    int kb = tid & ~31;
    float v[32];
    float m = -3.4e38f;
#pragma unroll
    for (int k = 0; k < 32; ++k) { v[k] = g1r[k] + gs[kb + k]; m = fmaxf(m, v[k]); }
    float s = 0.f;
#pragma unroll
    for (int k = 0; k < 32; ++k) s += __expf(v[k] - m);
    float lse = m + __logf(s);

    size_t idx = (size_t)b * HIDF + r;
    grad1[idx] = lse + lsech[idx];
}

// ---------------------------------------------------------------------------
// gemm2_splitk: out2p[kc][m][n] = sum_{k in chunk kc} h1b[m,k]*wn2b[n,k]
// A: 1024x2048 bf16, B: 64x2048 bf16. Block = 64(M) x 64(N) x 128(K-chunk).
// grid (16 kchunks, 16 mtiles), 256 threads (4 waves, each 16 rows x 64 n).
// Plain stores into per-chunk partial buffer (summed in tail_lite).
// ---------------------------------------------------------------------------
__global__ __launch_bounds__(256) void gemm2_splitk(
    const __hip_bfloat16* __restrict__ A, const __hip_bfloat16* __restrict__ B,
    float* __restrict__ out2p)
{
    __shared__ short As2[64 * 128];   // 16 KB [m][k]
    __shared__ short Bs2[64 * 128];   // 16 KB [n][k]
    int tid = threadIdx.x;
    int lane = tid & 63;
    int wave = tid >> 6;
    int k0 = blockIdx.x * 128;
    int m0 = blockIdx.y * 64;

    const char* Ab = (const char*)A;
    const char* Bb = (const char*)B;
#pragma unroll
    for (int is = 0; is < 4; ++is) {
        int ci = is * 256 + tid;          // 0..1023; row = ci>>4, kc = ci&15
        int row = ci >> 4, kc = ci & 15;
        char* ldsbase_a = (char*)As2 + (is * 256 + wave * 64) * 16;
        char* ldsbase_b = (char*)Bs2 + (is * 256 + wave * 64) * 16;
        gl_lds16(Ab + ((size_t)(m0 + row) * HIDF + k0) * 2 + kc * 16, ldsbase_a);
        gl_lds16(Bb + ((size_t)row * HIDF + k0) * 2 + kc * 16, ldsbase_b);
    }
    __syncthreads();

    int rf = lane & 15;
    int koff = (lane >> 4) * 8;

    floatx4 acc[4];
#pragma unroll
    for (int j = 0; j < 4; ++j) acc[j] = (floatx4){0.f, 0.f, 0.f, 0.f};

#pragma unroll
    for (int s = 0; s < 4; ++s) {
        short8 af = *(const short8*)&As2[(wave * 16 + rf) * 128 + s * 32 + koff];
#pragma unroll
        for (int j = 0; j < 4; ++j) {
            short8 bfv = *(const short8*)&Bs2[(j * 16 + rf) * 128 + s * 32 + koff];
            acc[j] = __builtin_amdgcn_mfma_f32_16x16x32_bf16(af, bfv, acc[j], 0, 0, 0);
        }
    }

    float* outk = out2p + (size_t)blockIdx.x * BATCH * DIMN;
    int col = lane & 15;
    int rq = (lane >> 4) * 4;
#pragma unroll
    for (int j = 0; j < 4; ++j) {
#pragma unroll
        for (int r = 0; r < 4; ++r) {
            int m = m0 + wave * 16 + rq + r;
            outk[(size_t)m * DIMN + j * 16 + col] = acc[j][r];
        }
    }
}

// ---------------------------------------------------------------------------
// tail_lite: per (b,n): o = b2[n] + sum_p out2p[p][b][n];
// gF = lse_k(g2[n*32+k] + grad1[b,n*32+k]);
// mode 0/1: gate-mix + reversed x_next + ldj write/accum
// mode 2:   out[b] = ldj[b] + sum_n(gF - 0.5*o^2 - 0.5*log(2pi))
// grid 256 blocks x 256 threads; wave = one batch row.
// ---------------------------------------------------------------------------
__global__ __launch_bounds__(256) void tail_lite(
    const float* __restrict__ out2p, const float* __restrict__ b2,
    const float* __restrict__ g2,
    const float* __restrict__ grad1, const float* __restrict__ x_cur,
    const float* __restrict__ gate, float* __restrict__ x_next,
    float* __restrict__ ldj, float* __restrict__ out, int mode)
{
    int tid = threadIdx.x;
    int b = blockIdx.x * 4 + (tid >> 6);
    int n = tid & 63;

    float o = b2[n];
#pragma unroll
    for (int p = 0; p < 16; ++p)
        o += out2p[(size_t)p * BATCH * DIMN + (size_t)b * DIMN + n];

    const float4* grow = (const float4*)(grad1 + (size_t)b * HIDF + n * 32);
    const float4* g2r = (const float4*)(g2 + n * 32);
    float v[32];
    float m = -3.4e38f;
#pragma unroll
    for (int q = 0; q < 8; ++q) {
        float4 gv = grow[q];
        float4 cv = g2r[q];
        v[q*4+0] = gv.x + cv.x; v[q*4+1] = gv.y + cv.y;
        v[q*4+2] = gv.z + cv.z; v[q*4+3] = gv.w + cv.w;
    }
#pragma unroll
    for (int k = 0; k < 32; ++k) m = fmaxf(m, v[k]);
    float s = 0.f;
#pragma unroll
    for (int k = 0; k < 32; ++k) s += __expf(v[k] - m);
    float gF = m + __logf(s);

    float contrib;
    if (mode < 2) {
        float gt = gate[0];
        float sg = 1.f / (1.f + __expf(-gt));
        float xo = sg * o + (1.f - sg) * x_cur[(size_t)b * DIMN + n];
        x_next[(size_t)b * DIMN + (63 - n)] = xo;
        contrib = softplusf_(gF + gt) - softplusf_(gt);
    } else {
        contrib = gF - 0.5f * o * o - 0.91893853320467274f; // -0.5*log(2pi)
    }
    for (int off = 32; off > 0; off >>= 1) contrib += __shfl_xor(contrib, off, 64);
    if (n == 0) {
        if (mode == 0)      ldj[b] = contrib;
        else if (mode == 1) ldj[b] += contrib;
        else                out[b] = ldj[b] + contrib;
    }
}

// ---------------------------------------------------------------------------
extern "C" void kernel_launch(void* const* d_in, const int* in_sizes, int n_in,
                              void* d_out, int out_size, void* d_ws, size_t ws_size,
                              hipStream_t stream)
{
    (void)in_sizes; (void)n_in; (void)out_size; (void)ws_size;

    const float* x = (const float*)d_in[0];
    const float* gates[2] = { (const float*)d_in[28], (const float*)d_in[29] };

    char* ws = (char*)d_ws;
    size_t ofs = 0;
    auto alloc = [&](size_t bytes) { char* p = ws + ofs; ofs += (bytes + 255) & ~(size_t)255; return p; };

    __hip_bfloat16* wn1  = (__hip_bfloat16*)alloc((size_t)HIDF * HIDF * 2);  // 8 MB
    __hip_bfloat16* h0   = (__hip_bfloat16*)alloc((size_t)BATCH * HIDF * 2); // 4 MB
    __hip_bfloat16* h1b  = (__hip_bfloat16*)alloc((size_t)BATCH * HIDF * 2); // 4 MB
    __hip_bfloat16* wn2b = (__hip_bfloat16*)alloc((size_t)DIMN * HIDF * 2);  // 256 KB
    float* lsech = (float*)alloc((size_t)BATCH * HIDF * 4);                  // 8 MB
    float* grad0 = (float*)alloc((size_t)BATCH * HIDF * 4);
    float* grad1 = (float*)alloc((size_t)BATCH * HIDF * 4);
    float* wn0T  = (float*)alloc((size_t)DIMN * HIDF * 4);
    float* g0    = (float*)alloc(HIDF * 4);
    float* g1    = (float*)alloc((size_t)HIDF * 32 * 4);
    float* g2    = (float*)alloc((size_t)DIMN * 32 * 4);
    float* out2p = (float*)alloc((size_t)16 * BATCH * DIMN * 4);             // 4 MB
    float* x1    = (float*)alloc((size_t)BATCH * DIMN * 4);
    float* x2    = (float*)alloc((size_t)BATCH * DIMN * 4);
    float* ldj   = (float*)alloc(BATCH * 4);
    float* outp  = (float*)d_out;

    const float* xcur = x;
    float* xnexts[3] = { x1, x2, nullptr };

    for (int f = 0; f < 3; ++f) {
        const float* W0  = (const float*)d_in[1 + f * 9 + 0];
        const float* dw0 = (const float*)d_in[1 + f * 9 + 1];
        const float* b0  = (const float*)d_in[1 + f * 9 + 2];
        const float* W1  = (const float*)d_in[1 + f * 9 + 3];
        const float* dw1 = (const float*)d_in[1 + f * 9 + 4];
        const float* b1  = (const float*)d_in[1 + f * 9 + 5];
        const float* W2  = (const float*)d_in[1 + f * 9 + 6];
        const float* dw2 = (const float*)d_in[1 + f * 9 + 7];
        const float* b2  = (const float*)d_in[1 + f * 9 + 8];

        prep_all<<<dim3(2 * HIDF + DIMN), dim3(64), 0, stream>>>(
            W0, dw0, wn0T, g0, W1, dw1, wn1, g1, W2, dw2, wn2b, g2);

        gemm0_act<<<dim3(8, BATCH / 16), dim3(256), 0, stream>>>(xcur, wn0T, b0, g0, h0, grad0);

        gemm1_act<<<dim3(HIDF / 64, BATCH / 64), dim3(256), 0, stream>>>(h0, wn1, b1, h1b, lsech);
        gradup1<<<dim3(HIDF / 256, BATCH), dim3(256), 0, stream>>>(lsech, grad0, g1, grad1);

        gemm2_splitk<<<dim3(HIDF / 128, BATCH / 64), dim3(256), 0, stream>>>(h1b, wn2b, out2p);

        tail_lite<<<dim3(BATCH / 4), dim3(256), 0, stream>>>(
            out2p, b2, g2, grad1, xcur,
            (f < 2) ? gates[f] : nullptr, xnexts[f], ldj, outp, f);

        xcur = (f == 0) ? x1 : x2;
    }
}

// Round 6
// 421.636 us; speedup vs baseline: 2.2446x; 1.0748x over previous
//
#include <hip/hip_runtime.h>
#include <hip/hip_bf16.h>
#include <math.h>

// ---------------------------------------------------------------------------
// BNAF flow (DIM=64, HID=32, B=1024).  R6: 11 dispatches.
// prep_mega (all flows) -> gemm0 -> [gemm1_fused -> gemm2_splitk -> tail_gemm0]x2
// -> gemm1_fused -> gemm2_splitk -> tail_final.
// gemm1 epilogue computes tanh + logsech2 + 32-term lse (gradup fused).
// ---------------------------------------------------------------------------

#define DIMN 64
#define BATCH 1024
#define HIDF 2048   // DIM*HID

typedef __attribute__((ext_vector_type(8))) short short8;
typedef __attribute__((ext_vector_type(4))) float floatx4;

__device__ __forceinline__ float softplusf_(float t) {
    return fmaxf(t, 0.f) + log1pf(__expf(-fabsf(t)));
}
// log(1 - tanh(x)^2) = -2*(x - log2 + softplus(-2x))
__device__ __forceinline__ float logsech2f_(float x) {
    return -2.f * (x - 0.6931471805599453f + softplusf_(-2.f * x));
}

__device__ __forceinline__ void gl_lds16(const void* g, void* l) {
    __builtin_amdgcn_global_load_lds(
        (const __attribute__((address_space(1))) unsigned int*)g,
        (__attribute__((address_space(3))) unsigned int*)l, 16, 0, 0);
}

// ---------------------------------------------------------------------------
// prep row worker: one wave per output row r of W (out_f x INF).
// ---------------------------------------------------------------------------
template<int INF>
__device__ __forceinline__ void prep_row(
    const float* __restrict__ W, const float* __restrict__ dw,
    void* __restrict__ wn_out, float* __restrict__ g,
    int r, int lane, int out_f, int ob, int ib, int transpose, int bf16out)
{
    constexpr int NI = INF / 64;
    int d = r / ob;
    int c0 = d * ib;
    int c1 = c0 + ib;
    const float* Wr = W + (size_t)r * INF;

    float vv[NI];
    float ss = 0.f;
#pragma unroll
    for (int i = 0; i < NI; ++i) {
        int c = lane + i * 64;
        float wraw = Wr[c];
        float wv = (c < c0) ? wraw : ((c < c1) ? __expf(wraw) : 0.f);
        vv[i] = wv;
        ss += wv * wv;
    }
    for (int off = 32; off > 0; off >>= 1) ss += __shfl_xor(ss, off, 64);

    float dwr = dw[r];
    float scale = __expf(dwr) / sqrtf(ss);
    float logt = dwr - 0.5f * __logf(ss);

#pragma unroll
    for (int i = 0; i < NI; ++i) {
        int c = lane + i * 64;
        float val = scale * vv[i];
        if (bf16out) {
            ((__hip_bfloat16*)wn_out)[(size_t)r * INF + c] = __float2bfloat16(val);
        } else if (transpose) {
            ((float*)wn_out)[(size_t)c * out_f + r] = val;
        } else {
            ((float*)wn_out)[(size_t)r * INF + c] = val;
        }
    }
    if (lane < ib) g[(size_t)r * ib + lane] = logt + Wr[c0 + lane];
}

struct PrepIn { const float *W0, *dw0, *W1, *dw1, *W2, *dw2; };

// all three flows' preps in ONE launch: grid 3 * (2048+2048+64) = 12480
__global__ __launch_bounds__(64) void prep_mega(
    PrepIn p0, PrepIn p1, PrepIn p2,
    float* __restrict__ wn0T_all, float* __restrict__ g0_all,
    __hip_bfloat16* __restrict__ wn1_all, float* __restrict__ g1_all,
    __hip_bfloat16* __restrict__ wn2b_all, float* __restrict__ g2_all)
{
    int blk = blockIdx.x;
    int lane = threadIdx.x;
    int f = blk / 4160;
    int rem = blk - f * 4160;
    PrepIn P = (f == 0) ? p0 : ((f == 1) ? p1 : p2);

    float* wn0T = wn0T_all + (size_t)f * DIMN * HIDF;
    float* g0   = g0_all   + (size_t)f * HIDF;
    __hip_bfloat16* wn1 = wn1_all + (size_t)f * HIDF * HIDF;
    float* g1   = g1_all   + (size_t)f * HIDF * 32;
    __hip_bfloat16* wn2b = wn2b_all + (size_t)f * DIMN * HIDF;
    float* g2   = g2_all   + (size_t)f * DIMN * 32;

    if (rem < HIDF) {
        // layer 0: W (2048,64), ob=32, ib=1, fp32 transposed (64x2048)
        prep_row<DIMN>(P.W0, P.dw0, wn0T, g0, rem, lane, HIDF, 32, 1, 1, 0);
    } else if (rem < 2 * HIDF) {
        // layer 1: W (2048,2048), ob=ib=32, bf16 natural
        prep_row<HIDF>(P.W1, P.dw1, wn1, g1, rem - HIDF, lane, HIDF, 32, 32, 0, 1);
    } else {
        // layer 2: W (64,2048), ob=1, ib=32, bf16 natural
        prep_row<HIDF>(P.W2, P.dw2, wn2b, g2, rem - 2 * HIDF, lane, DIMN, 1, 32, 0, 1);
    }
}

// ---------------------------------------------------------------------------
// gemm0 core (shared by gemm0_act and tail_gemm0 phase B):
// pre0 = xs @ wn0T + b0 ; h0 = tanh(pre0) bf16; grad0 = g0 + logsech2(pre0).
// xs: 16 batches x 64 dims in LDS. n = blockIdx.x*256 + tid.
// ---------------------------------------------------------------------------
__device__ __forceinline__ void gemm0_core(
    const float xs[16][DIMN], int b0, int n,
    const float* __restrict__ wn0T, const float* __restrict__ bias,
    const float* __restrict__ g0,
    __hip_bfloat16* __restrict__ h0, float* __restrict__ grad0)
{
    float acc[16];
#pragma unroll
    for (int j = 0; j < 16; ++j) acc[j] = 0.f;

#pragma unroll 4
    for (int c4 = 0; c4 < 16; ++c4) {
        int c = c4 * 4;
        float w0 = wn0T[(size_t)(c + 0) * HIDF + n];
        float w1 = wn0T[(size_t)(c + 1) * HIDF + n];
        float w2 = wn0T[(size_t)(c + 2) * HIDF + n];
        float w3 = wn0T[(size_t)(c + 3) * HIDF + n];
#pragma unroll
        for (int j = 0; j < 16; ++j) {
            float4 x4 = *(const float4*)&xs[j][c];
            acc[j] = fmaf(x4.x, w0, acc[j]);
            acc[j] = fmaf(x4.y, w1, acc[j]);
            acc[j] = fmaf(x4.z, w2, acc[j]);
            acc[j] = fmaf(x4.w, w3, acc[j]);
        }
    }
    float bv = bias[n], gv = g0[n];
#pragma unroll
    for (int j = 0; j < 16; ++j) {
        float p = acc[j] + bv;
        size_t idx = (size_t)(b0 + j) * HIDF + n;
        h0[idx] = __float2bfloat16(tanhf(p));
        grad0[idx] = gv + logsech2f_(p);
    }
}

// flow-0 gemm0: reads x directly (no reversal). grid (8, 64), 256 threads.
__global__ __launch_bounds__(256) void gemm0_act(
    const float* __restrict__ xin, const float* __restrict__ wn0T,
    const float* __restrict__ bias, const float* __restrict__ g0,
    __hip_bfloat16* __restrict__ h0, float* __restrict__ grad0)
{
    __shared__ float xs[16][DIMN];
    int b0 = blockIdx.y * 16;
    {
        const float4* src = (const float4*)(xin + (size_t)b0 * DIMN);
        ((float4*)xs)[threadIdx.x] = src[threadIdx.x];
    }
    __syncthreads();
    int n = blockIdx.x * 256 + threadIdx.x;
    gemm0_core(xs, b0, n, wn0T, bias, g0, h0, grad0);
}

// ---------------------------------------------------------------------------
// gemm1_fused: pre1 = h0 @ wn1^T + b1 (bf16 MFMA, 64x64 tile, BK=32).
// Epilogue: h1b = bf16(tanh(pre1));
//           grad1 = lse_k(g1[n*32+k] + grad0[m, (n&~31)+k]) + logsech2(pre1).
// grid (32, 16) = 512 blocks (2/CU), 256 threads (4 waves, 2x2 MFMA each).
// ---------------------------------------------------------------------------
#define G1K 32
__global__ __launch_bounds__(256) void gemm1_fused(
    const __hip_bfloat16* __restrict__ A, const __hip_bfloat16* __restrict__ B,
    const float* __restrict__ bias, const float* __restrict__ g1,
    const float* __restrict__ grad0,
    __hip_bfloat16* __restrict__ h1b, float* __restrict__ grad1)
{
    __shared__ char smem[25600];
    short* As = (short*)smem;                 // 4 KB [m][k]  (K-loop phase)
    short* Bs = (short*)(smem + 4096);        // 4 KB [n][k]
    float* g0s = (float*)smem;                // 16 KB [64 m][64 c]  (epilogue)
    float* g1s = (float*)(smem + 16384);      // 9216 B [64 n][36]   (epilogue)

    const int K = HIDF, N = HIDF;
    int tid = threadIdx.x;
    int lane = tid & 63;
    int wave = tid >> 6;
    int m0 = blockIdx.y * 64;
    int n0 = blockIdx.x * 64;
    int wr = wave & 1;    // m half (32 rows)
    int wc = wave >> 1;   // n half (32 cols)

    int ca = wave * 64 + lane;       // 16B chunk: row = ca>>2, kc = ca&3
    size_t aoff = ((size_t)(m0 + (ca >> 2)) * K) * 2 + (ca & 3) * 16;
    size_t boff = ((size_t)(n0 + (ca >> 2)) * K) * 2 + (ca & 3) * 16;
    const char* Abytes = (const char*)A;
    const char* Bbytes = (const char*)B;
    char* alds = (char*)As + wave * 1024;
    char* blds = (char*)Bs + wave * 1024;

    floatx4 acc[2][2];
#pragma unroll
    for (int i = 0; i < 2; ++i)
#pragma unroll
        for (int j = 0; j < 2; ++j) acc[i][j] = (floatx4){0.f, 0.f, 0.f, 0.f};

    int rf = lane & 15;
    int koff = (lane >> 4) * 8;

    for (int k0 = 0; k0 < K; k0 += G1K) {
        __syncthreads();
        size_t kb = (size_t)k0 * 2;
        gl_lds16(Abytes + aoff + kb, alds);
        gl_lds16(Bbytes + boff + kb, blds);
        __syncthreads();

        short8 af[2], bf[2];
#pragma unroll
        for (int i = 0; i < 2; ++i)
            af[i] = *(const short8*)&As[(wr * 32 + i * 16 + rf) * G1K + koff];
#pragma unroll
        for (int j = 0; j < 2; ++j)
            bf[j] = *(const short8*)&Bs[(wc * 32 + j * 16 + rf) * G1K + koff];
#pragma unroll
        for (int i = 0; i < 2; ++i)
#pragma unroll
            for (int j = 0; j < 2; ++j)
                acc[i][j] = __builtin_amdgcn_mfma_f32_16x16x32_bf16(af[i], bf[j], acc[i][j], 0, 0, 0);
    }

    // ---- epilogue: stage grad0 tile + g1 tile, then act + lse ----
    __syncthreads();
#pragma unroll
    for (int s = tid; s < 1024; s += 256) {      // grad0 64x64 floats
        int row = s >> 4, c4 = s & 15;
        *(float4*)&g0s[row * 64 + c4 * 4] =
            *(const float4*)&grad0[(size_t)(m0 + row) * HIDF + n0 + c4 * 4];
    }
#pragma unroll
    for (int s = tid; s < 512; s += 256) {       // g1 64x32 floats (pad 36)
        int row = s >> 3, c4 = s & 7;
        *(float4*)&g1s[row * 36 + c4 * 4] =
            *(const float4*)&g1[(size_t)(n0 + row) * 32 + c4 * 4];
    }
    __syncthreads();

    int col = lane & 15;
    int rq = (lane >> 4) * 4;
#pragma unroll
    for (int j = 0; j < 2; ++j) {
        int nloc = wc * 32 + j * 16 + col;
        int n = n0 + nloc;
        float bv = bias[n];
        float4 gl[8];
#pragma unroll
        for (int q = 0; q < 8; ++q) gl[q] = *(const float4*)&g1s[nloc * 36 + q * 4];
        int kb2 = nloc & 32;
#pragma unroll
        for (int i = 0; i < 2; ++i) {
#pragma unroll
            for (int r = 0; r < 4; ++r) {
                int mloc = wr * 32 + i * 16 + rq + r;
                const float* g0row = &g0s[mloc * 64 + kb2];
                float4 vv[8];
                float mx = -3.4e38f;
#pragma unroll
                for (int q = 0; q < 8; ++q) {
                    float4 gv = *(const float4*)&g0row[q * 4];
                    vv[q].x = gv.x + gl[q].x;
                    vv[q].y = gv.y + gl[q].y;
                    vv[q].z = gv.z + gl[q].z;
                    vv[q].w = gv.w + gl[q].w;
                    mx = fmaxf(mx, fmaxf(fmaxf(vv[q].x, vv[q].y), fmaxf(vv[q].z, vv[q].w)));
                }
                float ssum = 0.f;
#pragma unroll
                for (int q = 0; q < 8; ++q) {
                    ssum += __expf(vv[q].x - mx) + __expf(vv[q].y - mx)
                          + __expf(vv[q].z - mx) + __expf(vv[q].w - mx);
                }
                float lse = mx + __logf(ssum);
                float p = acc[i][j][r] + bv;
                size_t idx = (size_t)(m0 + mloc) * N + n;
                h1b[idx] = __float2bfloat16(tanhf(p));
                grad1[idx] = lse + logsech2f_(p);
            }
        }
    }
}

// ---------------------------------------------------------------------------
// gemm2_splitk: out2p[kc][m][n] = sum_{k in chunk kc} h1b[m,k]*wn2b[n,k]
// grid (16 kchunks, 16 mtiles), 256 threads.
// ---------------------------------------------------------------------------
__global__ __launch_bounds__(256) void gemm2_splitk(
    const __hip_bfloat16* __restrict__ A, const __hip_bfloat16* __restrict__ B,
    float* __restrict__ out2p)
{
    __shared__ short As2[64 * 128];   // 16 KB [m][k]
    __shared__ short Bs2[64 * 128];   // 16 KB [n][k]
    int tid = threadIdx.x;
    int lane = tid & 63;
    int wave = tid >> 6;
    int k0 = blockIdx.x * 128;
    int m0 = blockIdx.y * 64;

    const char* Ab = (const char*)A;
    const char* Bb = (const char*)B;
#pragma unroll
    for (int is = 0; is < 4; ++is) {
        int ci = is * 256 + tid;          // 0..1023; row = ci>>4, kc = ci&15
        int row = ci >> 4, kc = ci & 15;
        char* ldsbase_a = (char*)As2 + (is * 256 + wave * 64) * 16;
        char* ldsbase_b = (char*)Bs2 + (is * 256 + wave * 64) * 16;
        gl_lds16(Ab + ((size_t)(m0 + row) * HIDF + k0) * 2 + kc * 16, ldsbase_a);
        gl_lds16(Bb + ((size_t)row * HIDF + k0) * 2 + kc * 16, ldsbase_b);
    }
    __syncthreads();

    int rf = lane & 15;
    int koff = (lane >> 4) * 8;

    floatx4 acc[4];
#pragma unroll
    for (int j = 0; j < 4; ++j) acc[j] = (floatx4){0.f, 0.f, 0.f, 0.f};

#pragma unroll
    for (int s = 0; s < 4; ++s) {
        short8 af = *(const short8*)&As2[(wave * 16 + rf) * 128 + s * 32 + koff];
#pragma unroll
        for (int j = 0; j < 4; ++j) {
            short8 bfv = *(const short8*)&Bs2[(j * 16 + rf) * 128 + s * 32 + koff];
            acc[j] = __builtin_amdgcn_mfma_f32_16x16x32_bf16(af, bfv, acc[j], 0, 0, 0);
        }
    }

    float* outk = out2p + (size_t)blockIdx.x * BATCH * DIMN;
    int col = lane & 15;
    int rq = (lane >> 4) * 4;
#pragma unroll
    for (int j = 0; j < 4; ++j) {
#pragma unroll
        for (int r = 0; r < 4; ++r) {
            int m = m0 + wave * 16 + rq + r;
            outk[(size_t)m * DIMN + j * 16 + col] = acc[j][r];
        }
    }
}

// ---------------------------------------------------------------------------
// tail_gemm0: flows f -> f+1 transition fused with next flow's gemm0.
// Phase A (all blocks): o = b2 + sum_p out2p; xo = gate-mix; reversed into LDS.
//   blockIdx.x==0 additionally: write x_next, compute lse/ldj.
// Phase B: gemm0_core on the reversed x.
// grid (8, 64), 256 threads.
// ---------------------------------------------------------------------------
__global__ __launch_bounds__(256) void tail_gemm0(
    const float* __restrict__ out2p, const float* __restrict__ b2prev,
    const float* __restrict__ g2prev, const float* __restrict__ grad1,
    const float* __restrict__ x_cur, const float* __restrict__ gate,
    float* __restrict__ x_next, float* __restrict__ ldj, int accum_ldj,
    const float* __restrict__ wn0T, const float* __restrict__ bias0,
    const float* __restrict__ g0n, __hip_bfloat16* __restrict__ h0,
    float* __restrict__ grad0)
{
    __shared__ float xs[16][DIMN];
    int tid = threadIdx.x;
    int b0 = blockIdx.y * 16;

    {
        int bl = tid >> 4;            // local batch 0..15
        int n4 = (tid & 15) * 4;
        int b = b0 + bl;
        float4 o4 = *(const float4*)&b2prev[n4];
#pragma unroll
        for (int p = 0; p < 16; ++p) {
            float4 t = *(const float4*)&out2p[(size_t)p * BATCH * DIMN + (size_t)b * DIMN + n4];
            o4.x += t.x; o4.y += t.y; o4.z += t.z; o4.w += t.w;
        }
        float gt = gate[0];
        float sg = 1.f / (1.f + __expf(-gt));
        float4 xc = *(const float4*)&x_cur[(size_t)b * DIMN + n4];
        float4 xo;
        xo.x = sg * o4.x + (1.f - sg) * xc.x;
        xo.y = sg * o4.y + (1.f - sg) * xc.y;
        xo.z = sg * o4.z + (1.f - sg) * xc.z;
        xo.w = sg * o4.w + (1.f - sg) * xc.w;
        // reversed into LDS (this IS the next flow's x)
        xs[bl][63 - n4] = xo.x;
        xs[bl][62 - n4] = xo.y;
        xs[bl][61 - n4] = xo.z;
        xs[bl][60 - n4] = xo.w;

        if (blockIdx.x == 0) {
            float4 rv; rv.x = xo.w; rv.y = xo.z; rv.z = xo.y; rv.w = xo.x;
            *(float4*)&x_next[(size_t)b * DIMN + (60 - n4)] = rv;

            float spgt = softplusf_(gt);
            float cl = 0.f;
#pragma unroll
            for (int q = 0; q < 4; ++q) {
                int n = n4 + q;
                const float4* gr = (const float4*)&grad1[(size_t)b * HIDF + n * 32];
                const float4* gc = (const float4*)&g2prev[n * 32];
                float4 vv[8];
                float mx = -3.4e38f;
#pragma unroll
                for (int u = 0; u < 8; ++u) {
                    float4 a = gr[u], c = gc[u];
                    vv[u].x = a.x + c.x; vv[u].y = a.y + c.y;
                    vv[u].z = a.z + c.z; vv[u].w = a.w + c.w;
                    mx = fmaxf(mx, fmaxf(fmaxf(vv[u].x, vv[u].y), fmaxf(vv[u].z, vv[u].w)));
                }
                float ssum = 0.f;
#pragma unroll
                for (int u = 0; u < 8; ++u) {
                    ssum += __expf(vv[u].x - mx) + __expf(vv[u].y - mx)
                          + __expf(vv[u].z - mx) + __expf(vv[u].w - mx);
                }
                float gF = mx + __logf(ssum);
                cl += softplusf_(gF + gt) - spgt;
            }
            cl += __shfl_xor(cl, 1, 64);
            cl += __shfl_xor(cl, 2, 64);
            cl += __shfl_xor(cl, 4, 64);
            cl += __shfl_xor(cl, 8, 64);
            if ((tid & 15) == 0) ldj[b] = accum_ldj ? (ldj[b] + cl) : cl;
        }
    }
    __syncthreads();

    int n = blockIdx.x * 256 + tid;
    gemm0_core(xs, b0, n, wn0T, bias0, g0n, h0, grad0);
}

// ---------------------------------------------------------------------------
// tail_final (flow 2): out[b] = ldj[b] + sum_n(gF - 0.5*o^2 - 0.5*log(2pi))
// grid 256, 256 threads; wave = one batch row.
// ---------------------------------------------------------------------------
__global__ __launch_bounds__(256) void tail_final(
    const float* __restrict__ out2p, const float* __restrict__ b2,
    const float* __restrict__ g2, const float* __restrict__ grad1,
    const float* __restrict__ ldj, float* __restrict__ out)
{
    int tid = threadIdx.x;
    int b = blockIdx.x * 4 + (tid >> 6);
    int n = tid & 63;

    float o = b2[n];
#pragma unroll
    for (int p = 0; p < 16; ++p)
        o += out2p[(size_t)p * BATCH * DIMN + (size_t)b * DIMN + n];

    const float4* grow = (const float4*)(grad1 + (size_t)b * HIDF + n * 32);
    const float4* g2r = (const float4*)(g2 + n * 32);
    float4 vv[8];
    float mx = -3.4e38f;
#pragma unroll
    for (int q = 0; q < 8; ++q) {
        float4 a = grow[q], c = g2r[q];
        vv[q].x = a.x + c.x; vv[q].y = a.y + c.y;
        vv[q].z = a.z + c.z; vv[q].w = a.w + c.w;
        mx = fmaxf(mx, fmaxf(fmaxf(vv[q].x, vv[q].y), fmaxf(vv[q].z, vv[q].w)));
    }
    float s = 0.f;
#pragma unroll
    for (int q = 0; q < 8; ++q) {
        s += __expf(vv[q].x - mx) + __expf(vv[q].y - mx)
           + __expf(vv[q].z - mx) + __expf(vv[q].w - mx);
    }
    float gF = mx + __logf(s);

    float contrib = gF - 0.5f * o * o - 0.91893853320467274f; // -0.5*log(2pi)
    for (int off = 32; off > 0; off >>= 1) contrib += __shfl_xor(contrib, off, 64);
    if (n == 0) out[b] = ldj[b] + contrib;
}

// ---------------------------------------------------------------------------
extern "C" void kernel_launch(void* const* d_in, const int* in_sizes, int n_in,
                              void* d_out, int out_size, void* d_ws, size_t ws_size,
                              hipStream_t stream)
{
    (void)in_sizes; (void)n_in; (void)out_size; (void)ws_size;

    const float* x = (const float*)d_in[0];
    const float* gates[2] = { (const float*)d_in[28], (const float*)d_in[29] };

    char* ws = (char*)d_ws;
    size_t ofs = 0;
    auto alloc = [&](size_t bytes) { char* p = ws + ofs; ofs += (bytes + 255) & ~(size_t)255; return p; };

    __hip_bfloat16* wn1_all  = (__hip_bfloat16*)alloc((size_t)3 * HIDF * HIDF * 2);  // 24 MB
    __hip_bfloat16* wn2b_all = (__hip_bfloat16*)alloc((size_t)3 * DIMN * HIDF * 2);
    float* wn0T_all = (float*)alloc((size_t)3 * DIMN * HIDF * 4);
    float* g0_all   = (float*)alloc((size_t)3 * HIDF * 4);
    float* g1_all   = (float*)alloc((size_t)3 * HIDF * 32 * 4);
    float* g2_all   = (float*)alloc((size_t)3 * DIMN * 32 * 4);
    __hip_bfloat16* h0  = (__hip_bfloat16*)alloc((size_t)BATCH * HIDF * 2);
    __hip_bfloat16* h1b = (__hip_bfloat16*)alloc((size_t)BATCH * HIDF * 2);
    float* grad0 = (float*)alloc((size_t)BATCH * HIDF * 4);
    float* grad1 = (float*)alloc((size_t)BATCH * HIDF * 4);
    float* out2p = (float*)alloc((size_t)16 * BATCH * DIMN * 4);
    float* x1    = (float*)alloc((size_t)BATCH * DIMN * 4);
    float* x2    = (float*)alloc((size_t)BATCH * DIMN * 4);
    float* ldj   = (float*)alloc(BATCH * 4);
    float* outp  = (float*)d_out;

    auto W = [&](int f, int i) { return (const float*)d_in[1 + f * 9 + i]; };

    PrepIn p0 = { W(0,0), W(0,1), W(0,3), W(0,4), W(0,6), W(0,7) };
    PrepIn p1 = { W(1,0), W(1,1), W(1,3), W(1,4), W(1,6), W(1,7) };
    PrepIn p2 = { W(2,0), W(2,1), W(2,3), W(2,4), W(2,6), W(2,7) };

    prep_mega<<<dim3(3 * 4160), dim3(64), 0, stream>>>(
        p0, p1, p2, wn0T_all, g0_all, wn1_all, g1_all, wn2b_all, g2_all);

    // flow 0 gemm0 (reads x directly)
    gemm0_act<<<dim3(8, BATCH / 16), dim3(256), 0, stream>>>(
        x, wn0T_all, W(0,2), g0_all, h0, grad0);

    const float* xcur = x;
    float* xnexts[2] = { x1, x2 };

    for (int f = 0; f < 3; ++f) {
        size_t fo1 = (size_t)f * HIDF * HIDF;
        size_t fo2 = (size_t)f * DIMN * HIDF;

        gemm1_fused<<<dim3(HIDF / 64, BATCH / 64), dim3(256), 0, stream>>>(
            h0, wn1_all + fo1, W(f,5), g1_all + (size_t)f * HIDF * 32, grad0, h1b, grad1);

        gemm2_splitk<<<dim3(HIDF / 128, BATCH / 64), dim3(256), 0, stream>>>(
            h1b, wn2b_all + fo2, out2p);

        if (f < 2) {
            tail_gemm0<<<dim3(8, BATCH / 16), dim3(256), 0, stream>>>(
                out2p, W(f,8), g2_all + (size_t)f * DIMN * 32, grad1,
                xcur, gates[f], xnexts[f], ldj, f,
                wn0T_all + (size_t)(f + 1) * DIMN * HIDF, W(f + 1, 2),
                g0_all + (size_t)(f + 1) * HIDF, h0, grad0);
            xcur = xnexts[f];
        } else {
            tail_final<<<dim3(BATCH / 4), dim3(256), 0, stream>>>(
                out2p, W(2,8), g2_all + (size_t)2 * DIMN * 32, grad1, ldj, outp);
        }
    }
}